// Round 1
// baseline (9525.198 us; speedup 1.0000x reference)
//
#include <hip/hip_runtime.h>
#include <math.h>

#define B 2048
#define M 65536
#define H 128
#define TDIM 128
#define IDIM 256
#define SC 32           // stats chunks over M
#define SCHUNK (M / SC) // 2048

// ---------------- K1: prep  q~ = (cos-enc @ Wq^T) @ Wk,  v_h = inp @ Wv^T ----
__global__ __launch_bounds__(128) void k_prep(const float* __restrict__ ts,
        const float* __restrict__ inp, const float* __restrict__ w_t,
        const float* __restrict__ b_t, const float* __restrict__ Wq,
        const float* __restrict__ Wk, const float* __restrict__ Wv,
        float* __restrict__ qt, float* __restrict__ vh) {
    __shared__ float temb[TDIM];
    __shared__ float qh[H];
    const int b = blockIdx.x, t = threadIdx.x;
    const float tv = ts[b];
    temb[t] = cosf(tv * w_t[t] + b_t[t]);
    __syncthreads();
    // q_h[j] = sum_t temb[t] * Wq[j][t]
    float s = 0.f;
    for (int k = 0; k < TDIM; k++) s += temb[k] * Wq[t * TDIM + k];
    qh[t] = s;
    __syncthreads();
    // q~[t] = sum_j q_h[j] * Wk[j][t]
    float s2 = 0.f;
    for (int j = 0; j < H; j++) s2 += qh[j] * Wk[j * H + t];
    qt[(size_t)b * H + t] = s2;
    // v_h[j] = sum_i inp[b][i] * Wv[j][i]
    float s3 = 0.f;
    for (int i = 0; i < IDIM; i++) s3 += inp[(size_t)b * IDIM + i] * Wv[t * IDIM + i];
    vh[(size_t)b * H + t] = s3;
}

// ------------- K2/K5: per-(b, m-chunk) online max & sumexp of S = scale * q~ . src[m] -
__global__ __launch_bounds__(256) void k_stats(const float* __restrict__ src,
        const float* __restrict__ qt, float scale,
        float* __restrict__ pmax, float* __restrict__ psum) {
    const int tid = threadIdx.x;
    const int half = (tid >> 5) & 1;                  // K-half owned by this lane
    const int bl = (tid & 31) + ((tid >> 6) << 5);    // lane l and l^32 share b
    const int b = blockIdx.x * 128 + bl;
    const int m0 = blockIdx.y * SCHUNK;
    float4 q[16];
    const float4* qp = (const float4*)(qt + (size_t)b * H + half * 64);
#pragma unroll
    for (int j = 0; j < 16; j++) q[j] = qp[j];
    float mx = -INFINITY, sm = 0.f;
    for (int m = m0; m < m0 + SCHUNK; m++) {
        const float4* mr = (const float4*)(src + (size_t)m * H + half * 64);
        float s = 0.f;
#pragma unroll
        for (int j = 0; j < 16; j++) {
            float4 a = q[j], c = mr[j];
            s += a.x * c.x + a.y * c.y + a.z * c.z + a.w * c.w;
        }
        s += __shfl_xor(s, 32);   // combine the two K-halves
        s *= scale;
        float nm = fmaxf(mx, s);
        sm = sm * __expf(mx - nm) + __expf(s - nm);
        mx = nm;
    }
    if (half == 0) {
        pmax[(size_t)b * SC + blockIdx.y] = mx;
        psum[(size_t)b * SC + blockIdx.y] = sm;
    }
}

// ------------- K3/K6: combine chunk stats -> global max, 1/Z per row b -------
__global__ __launch_bounds__(256) void k_combine(const float* __restrict__ pmax,
        const float* __restrict__ psum, float* __restrict__ gmax,
        float* __restrict__ ginv) {
    const int b = blockIdx.x * 256 + threadIdx.x;
    float mx = -INFINITY;
    for (int c = 0; c < SC; c++) mx = fmaxf(mx, pmax[(size_t)b * SC + c]);
    float z = 0.f;
    for (int c = 0; c < SC; c++)
        z += psum[(size_t)b * SC + c] * __expf(pmax[(size_t)b * SC + c] - mx);
    gmax[b] = mx;
    ginv[b] = 1.f / z;
}

// ------------- K4: mem = normalize(memory + P1^T @ v_h) ----------------------
__global__ __launch_bounds__(256) void k_update(const float* __restrict__ memory,
        const float* __restrict__ qt, const float* __restrict__ vh,
        const float* __restrict__ gmax, const float* __restrict__ ginv,
        float* __restrict__ memw) {
    const int tid = threadIdx.x;
    const int half = (tid >> 5) & 1;
    const int ml = (tid & 31) + ((tid >> 6) << 5);
    const int m = blockIdx.x * 128 + ml;
    float4 mreg[16], acc[16];
    const float4* mp = (const float4*)(memory + (size_t)m * H + half * 64);
#pragma unroll
    for (int j = 0; j < 16; j++) { mreg[j] = mp[j]; acc[j] = make_float4(0.f, 0.f, 0.f, 0.f); }
    for (int b = 0; b < B; b++) {
        const float4* qp = (const float4*)(qt + (size_t)b * H + half * 64);
        float s = 0.f;
#pragma unroll
        for (int j = 0; j < 16; j++) {
            float4 a = qp[j], c = mreg[j];
            s += a.x * c.x + a.y * c.y + a.z * c.z + a.w * c.w;
        }
        s += __shfl_xor(s, 32);
        const float p = __expf(s - gmax[b]) * ginv[b];
        const float4* vp = (const float4*)(vh + (size_t)b * H + half * 64);
#pragma unroll
        for (int j = 0; j < 16; j++) {
            float4 v = vp[j];
            acc[j].x += p * v.x; acc[j].y += p * v.y;
            acc[j].z += p * v.z; acc[j].w += p * v.w;
        }
    }
    float n2 = 0.f;
#pragma unroll
    for (int j = 0; j < 16; j++) {
        acc[j].x += mreg[j].x; acc[j].y += mreg[j].y;
        acc[j].z += mreg[j].z; acc[j].w += mreg[j].w;
        n2 += acc[j].x * acc[j].x + acc[j].y * acc[j].y
            + acc[j].z * acc[j].z + acc[j].w * acc[j].w;
    }
    n2 += __shfl_xor(n2, 32);
    const float sc = 1.f / fmaxf(sqrtf(n2), 1e-12f);
    float4* op = (float4*)(memw + (size_t)m * H + half * 64);
#pragma unroll
    for (int j = 0; j < 16; j++) {
        float4 o = acc[j];
        o.x *= sc; o.y *= sc; o.z *= sc; o.w *= sc;
        op[j] = o;
    }
}

// ------------- K7: partial read_r over m-chunks ------------------------------
__global__ __launch_bounds__(256) void k_read(const float* __restrict__ memw,
        const float* __restrict__ qt, const float* __restrict__ gmax,
        const float* __restrict__ ginv, float* __restrict__ part, int mchunk) {
    const int tid = threadIdx.x;
    const int half = (tid >> 5) & 1;
    const int bl = (tid & 31) + ((tid >> 6) << 5);
    const int b = blockIdx.x * 128 + bl;
    const int m0 = blockIdx.y * mchunk;
    const float scale = 0.08838834764831845f; // 1/sqrt(128)
    float4 q[16], acc[16];
    const float4* qp = (const float4*)(qt + (size_t)b * H + half * 64);
#pragma unroll
    for (int j = 0; j < 16; j++) { q[j] = qp[j]; acc[j] = make_float4(0.f, 0.f, 0.f, 0.f); }
    const float gm = gmax[b], gi = ginv[b];
    for (int m = m0; m < m0 + mchunk; m++) {
        const float4* mr = (const float4*)(memw + (size_t)m * H + half * 64);
        float4 c0[16];
        float s = 0.f;
#pragma unroll
        for (int j = 0; j < 16; j++) {
            c0[j] = mr[j];
            s += q[j].x * c0[j].x + q[j].y * c0[j].y + q[j].z * c0[j].z + q[j].w * c0[j].w;
        }
        s += __shfl_xor(s, 32);
        const float p = __expf(s * scale - gm) * gi;
#pragma unroll
        for (int j = 0; j < 16; j++) {
            acc[j].x += p * c0[j].x; acc[j].y += p * c0[j].y;
            acc[j].z += p * c0[j].z; acc[j].w += p * c0[j].w;
        }
    }
    float4* pp = (float4*)(part + ((size_t)blockIdx.y * B + b) * H + half * 64);
#pragma unroll
    for (int j = 0; j < 16; j++) pp[j] = acc[j];
}

// ------------- K8: reduce partials -> out ------------------------------------
__global__ __launch_bounds__(256) void k_reduce(const float* __restrict__ part,
        float* __restrict__ out, int nc) {
    const int i = blockIdx.x * 256 + threadIdx.x; // over B*H
    float s = 0.f;
    for (int c = 0; c < nc; c++) s += part[(size_t)c * B * H + i];
    out[i] = s;
}

extern "C" void kernel_launch(void* const* d_in, const int* in_sizes, int n_in,
                              void* d_out, int out_size, void* d_ws, size_t ws_size,
                              hipStream_t stream) {
    const float* ts     = (const float*)d_in[0];
    const float* inp    = (const float*)d_in[1];
    const float* memory = (const float*)d_in[2];
    const float* w_t    = (const float*)d_in[3];
    const float* b_t    = (const float*)d_in[4];
    const float* Wq     = (const float*)d_in[5];
    const float* Wk     = (const float*)d_in[6];
    const float* Wv     = (const float*)d_in[7];
    float* out = (float*)d_out;

    float* ws   = (float*)d_ws;
    float* qt   = ws;                       // [B][H]
    float* vh   = qt + (size_t)B * H;       // [B][H]
    float* memw = vh + (size_t)B * H;       // [M][H]
    float* pmax = memw + (size_t)M * H;     // [B][SC]
    float* psum = pmax + (size_t)B * SC;    // [B][SC]
    float* gmax = psum + (size_t)B * SC;    // [B]
    float* ginv = gmax + B;                 // [B]
    float* part = ginv + B;                 // [nc][B][H]

    const size_t base_bytes = (size_t)(part - ws) * sizeof(float);
    int nc = 1;
    for (int c = 32; c >= 1; c >>= 1) {
        if (base_bytes + (size_t)c * B * H * sizeof(float) <= ws_size) { nc = c; break; }
    }
    const int mchunk = M / nc;

    hipLaunchKernelGGL(k_prep, dim3(B), dim3(128), 0, stream,
                       ts, inp, w_t, b_t, Wq, Wk, Wv, qt, vh);
    // pass 1: softmax stats (no scale)
    hipLaunchKernelGGL(k_stats, dim3(16, SC), dim3(256), 0, stream,
                       memory, qt, 1.0f, pmax, psum);
    hipLaunchKernelGGL(k_combine, dim3(8), dim3(256), 0, stream, pmax, psum, gmax, ginv);
    // memory update + L2 normalize
    hipLaunchKernelGGL(k_update, dim3(M / 128), dim3(256), 0, stream,
                       memory, qt, vh, gmax, ginv, memw);
    // pass 2: softmax stats (scaled)
    hipLaunchKernelGGL(k_stats, dim3(16, SC), dim3(256), 0, stream,
                       memw, qt, 0.08838834764831845f, pmax, psum);
    hipLaunchKernelGGL(k_combine, dim3(8), dim3(256), 0, stream, pmax, psum, gmax, ginv);
    // attention read
    hipLaunchKernelGGL(k_read, dim3(16, nc), dim3(256), 0, stream,
                       memw, qt, gmax, ginv, part, mchunk);
    hipLaunchKernelGGL(k_reduce, dim3(B * H / 256), dim3(256), 0, stream, part, out, nc);
}

// Round 2
// 8981.208 us; speedup vs baseline: 1.0606x; 1.0606x over previous
//
#include <hip/hip_runtime.h>
#include <math.h>

#define B 2048
#define M 65536
#define H 128
#define TDIM 128
#define IDIM 256
#define SC 64           // stats chunks over M
#define SCHUNK (M / SC) // 1024

#define DOT4(s, a, c) s += (a).x*(c).x + (a).y*(c).y + (a).z*(c).z + (a).w*(c).w

// ---------------- K1: prep  q~ = (cos-enc @ Wq^T) @ Wk,  v_h = inp @ Wv^T ----
__global__ __launch_bounds__(128) void k_prep(const float* __restrict__ ts,
        const float* __restrict__ inp, const float* __restrict__ w_t,
        const float* __restrict__ b_t, const float* __restrict__ Wq,
        const float* __restrict__ Wk, const float* __restrict__ Wv,
        float* __restrict__ qt, float* __restrict__ vh) {
    __shared__ float temb[TDIM];
    __shared__ float qh[H];
    const int b = blockIdx.x, t = threadIdx.x;
    const float tv = ts[b];
    temb[t] = cosf(tv * w_t[t] + b_t[t]);
    __syncthreads();
    float s = 0.f;
    for (int k = 0; k < TDIM; k++) s += temb[k] * Wq[t * TDIM + k];
    qh[t] = s;
    __syncthreads();
    float s2 = 0.f;
    for (int j = 0; j < H; j++) s2 += qh[j] * Wk[j * H + t];
    qt[(size_t)b * H + t] = s2;
    float s3 = 0.f;
    for (int i = 0; i < IDIM; i++) s3 += inp[(size_t)b * IDIM + i] * Wv[t * IDIM + i];
    vh[(size_t)b * H + t] = s3;
}

// ------- K2/K5: per-(b, m-chunk) deferred-max sumexp of S = scale * q~ . src[m]
// K split 4-way across lane quads {l, l^16, l^32, l^48}; 2 b's per thread.
__global__ __launch_bounds__(256) void k_stats(const float* __restrict__ src,
        const float* __restrict__ qt, float scale,
        float* __restrict__ pmax, float* __restrict__ psum) {
    const int tid = threadIdx.x;
    const int qi = (tid >> 4) & 3;                    // K-quarter owned
    const int rl = (tid & 15) + ((tid >> 6) << 4);    // [0,64)
    const int b0 = blockIdx.x * 128 + rl * 2;
    const int m0 = blockIdx.y * SCHUNK;
    float4 q0[8], q1[8];
    const float4* qp0 = (const float4*)(qt + (size_t)b0 * H);
    const float4* qp1 = (const float4*)(qt + (size_t)(b0 + 1) * H);
#pragma unroll
    for (int j = 0; j < 8; j++) { q0[j] = qp0[qi + 4*j]; q1[j] = qp1[qi + 4*j]; }
    float mb0 = -INFINITY, sm0 = 0.f, mb1 = -INFINITY, sm1 = 0.f;
    for (int m = m0; m < m0 + SCHUNK; m++) {
        const float4* mr = (const float4*)(src + (size_t)m * H);
        float s0 = 0.f, s1 = 0.f;
#pragma unroll
        for (int j = 0; j < 8; j++) {
            float4 c = mr[qi + 4*j];
            DOT4(s0, q0[j], c);
            DOT4(s1, q1[j], c);
        }
        s0 += __shfl_xor(s0, 16); s0 += __shfl_xor(s0, 32);
        s1 += __shfl_xor(s1, 16); s1 += __shfl_xor(s1, 32);
        s0 *= scale; s1 *= scale;
        float d0 = s0 - mb0;
        if (d0 > 8.f) { sm0 *= __expf(-d0); mb0 = s0; d0 = 0.f; }
        sm0 += __expf(d0);
        float d1 = s1 - mb1;
        if (d1 > 8.f) { sm1 *= __expf(-d1); mb1 = s1; d1 = 0.f; }
        sm1 += __expf(d1);
    }
    if (qi == 0) {
        pmax[(size_t)b0 * SC + blockIdx.y] = mb0;
        psum[(size_t)b0 * SC + blockIdx.y] = sm0;
        pmax[(size_t)(b0 + 1) * SC + blockIdx.y] = mb1;
        psum[(size_t)(b0 + 1) * SC + blockIdx.y] = sm1;
    }
}

// ------------- K3/K6: combine chunk stats -> global max-offset, 1/Z ----------
__global__ __launch_bounds__(256) void k_combine(const float* __restrict__ pmax,
        const float* __restrict__ psum, float* __restrict__ gmax,
        float* __restrict__ ginv) {
    const int b = blockIdx.x * 256 + threadIdx.x;
    float mx = -INFINITY;
    for (int c = 0; c < SC; c++) mx = fmaxf(mx, pmax[(size_t)b * SC + c]);
    float z = 0.f;
    for (int c = 0; c < SC; c++)
        z += psum[(size_t)b * SC + c] * __expf(pmax[(size_t)b * SC + c] - mx);
    gmax[b] = mx;
    ginv[b] = 1.f / z;
}

// ------------- K4: mem = normalize(memory + P1^T @ v_h) ----------------------
// Each lane quad owns one m-row (K quartered, interleaved float4s); loop b by 2.
__global__ __launch_bounds__(256) void k_update(const float* __restrict__ memory,
        const float* __restrict__ qt, const float* __restrict__ vh,
        const float* __restrict__ gmax, const float* __restrict__ ginv,
        float* __restrict__ memw) {
    const int tid = threadIdx.x;
    const int qi = (tid >> 4) & 3;
    const int rl = (tid & 15) + ((tid >> 6) << 4);    // [0,64)
    const int m = blockIdx.x * 64 + rl;
    float4 mreg[8], acc[8];
    const float4* mp = (const float4*)(memory + (size_t)m * H);
#pragma unroll
    for (int j = 0; j < 8; j++) { mreg[j] = mp[qi + 4*j]; acc[j] = make_float4(0.f,0.f,0.f,0.f); }
    for (int b = 0; b < B; b += 2) {
        const float4* qp0 = (const float4*)(qt + (size_t)b * H);
        const float4* qp1 = (const float4*)(qt + (size_t)(b + 1) * H);
        float s0 = 0.f, s1 = 0.f;
#pragma unroll
        for (int j = 0; j < 8; j++) {
            float4 a0 = qp0[qi + 4*j], a1 = qp1[qi + 4*j];
            DOT4(s0, a0, mreg[j]);
            DOT4(s1, a1, mreg[j]);
        }
        s0 += __shfl_xor(s0, 16); s0 += __shfl_xor(s0, 32);
        s1 += __shfl_xor(s1, 16); s1 += __shfl_xor(s1, 32);
        const float p0 = __expf(s0 - gmax[b]) * ginv[b];
        const float p1 = __expf(s1 - gmax[b + 1]) * ginv[b + 1];
        const float4* vp0 = (const float4*)(vh + (size_t)b * H);
        const float4* vp1 = (const float4*)(vh + (size_t)(b + 1) * H);
#pragma unroll
        for (int j = 0; j < 8; j++) {
            float4 v0 = vp0[qi + 4*j], v1 = vp1[qi + 4*j];
            acc[j].x += p0 * v0.x; acc[j].y += p0 * v0.y;
            acc[j].z += p0 * v0.z; acc[j].w += p0 * v0.w;
            acc[j].x += p1 * v1.x; acc[j].y += p1 * v1.y;
            acc[j].z += p1 * v1.z; acc[j].w += p1 * v1.w;
        }
    }
    float n2 = 0.f;
#pragma unroll
    for (int j = 0; j < 8; j++) {
        acc[j].x += mreg[j].x; acc[j].y += mreg[j].y;
        acc[j].z += mreg[j].z; acc[j].w += mreg[j].w;
        n2 += acc[j].x*acc[j].x + acc[j].y*acc[j].y + acc[j].z*acc[j].z + acc[j].w*acc[j].w;
    }
    n2 += __shfl_xor(n2, 16); n2 += __shfl_xor(n2, 32);
    const float sc = 1.f / fmaxf(sqrtf(n2), 1e-12f);
    float4* op = (float4*)(memw + (size_t)m * H);
#pragma unroll
    for (int j = 0; j < 8; j++) {
        float4 o = acc[j];
        o.x *= sc; o.y *= sc; o.z *= sc; o.w *= sc;
        op[qi + 4*j] = o;
    }
}

// ------------- K7: partial read_r over m-chunks (K quartered, 2 m's/iter) ----
__global__ __launch_bounds__(256) void k_read(const float* __restrict__ memw,
        const float* __restrict__ qt, const float* __restrict__ gmax,
        const float* __restrict__ ginv, float* __restrict__ part, int mchunk) {
    const int tid = threadIdx.x;
    const int qi = (tid >> 4) & 3;
    const int rl = (tid & 15) + ((tid >> 6) << 4);    // [0,64)
    const int b = blockIdx.x * 64 + rl;
    const int m0 = blockIdx.y * mchunk;
    const float scale = 0.08838834764831845f; // 1/sqrt(128)
    float4 q[8], acc[8];
    const float4* qp = (const float4*)(qt + (size_t)b * H);
#pragma unroll
    for (int j = 0; j < 8; j++) { q[j] = qp[qi + 4*j]; acc[j] = make_float4(0.f,0.f,0.f,0.f); }
    const float gm = gmax[b], gi = ginv[b];
    for (int m = m0; m < m0 + mchunk; m += 2) {
        const float4* mr0 = (const float4*)(memw + (size_t)m * H);
        const float4* mr1 = (const float4*)(memw + (size_t)(m + 1) * H);
        float4 c0[8], c1[8];
        float s0 = 0.f, s1 = 0.f;
#pragma unroll
        for (int j = 0; j < 8; j++) {
            c0[j] = mr0[qi + 4*j]; c1[j] = mr1[qi + 4*j];
            DOT4(s0, q[j], c0[j]);
            DOT4(s1, q[j], c1[j]);
        }
        s0 += __shfl_xor(s0, 16); s0 += __shfl_xor(s0, 32);
        s1 += __shfl_xor(s1, 16); s1 += __shfl_xor(s1, 32);
        const float p0 = __expf(s0 * scale - gm) * gi;
        const float p1 = __expf(s1 * scale - gm) * gi;
#pragma unroll
        for (int j = 0; j < 8; j++) {
            acc[j].x += p0 * c0[j].x; acc[j].y += p0 * c0[j].y;
            acc[j].z += p0 * c0[j].z; acc[j].w += p0 * c0[j].w;
            acc[j].x += p1 * c1[j].x; acc[j].y += p1 * c1[j].y;
            acc[j].z += p1 * c1[j].z; acc[j].w += p1 * c1[j].w;
        }
    }
    float4* pp = (float4*)(part + ((size_t)blockIdx.y * B + b) * H);
#pragma unroll
    for (int j = 0; j < 8; j++) pp[qi + 4*j] = acc[j];
}

// ------------- K8: reduce partials -> out ------------------------------------
__global__ __launch_bounds__(256) void k_reduce(const float* __restrict__ part,
        float* __restrict__ out, int nc) {
    const int i = blockIdx.x * 256 + threadIdx.x; // over B*H
    float s = 0.f;
    for (int c = 0; c < nc; c++) s += part[(size_t)c * B * H + i];
    out[i] = s;
}

extern "C" void kernel_launch(void* const* d_in, const int* in_sizes, int n_in,
                              void* d_out, int out_size, void* d_ws, size_t ws_size,
                              hipStream_t stream) {
    const float* ts     = (const float*)d_in[0];
    const float* inp    = (const float*)d_in[1];
    const float* memory = (const float*)d_in[2];
    const float* w_t    = (const float*)d_in[3];
    const float* b_t    = (const float*)d_in[4];
    const float* Wq     = (const float*)d_in[5];
    const float* Wk     = (const float*)d_in[6];
    const float* Wv     = (const float*)d_in[7];
    float* out = (float*)d_out;

    float* ws   = (float*)d_ws;
    float* qt   = ws;                       // [B][H]
    float* vh   = qt + (size_t)B * H;       // [B][H]
    float* memw = vh + (size_t)B * H;       // [M][H]
    float* pmax = memw + (size_t)M * H;     // [B][SC]
    float* psum = pmax + (size_t)B * SC;    // [B][SC]
    float* gmax = psum + (size_t)B * SC;    // [B]
    float* ginv = gmax + B;                 // [B]
    float* part = ginv + B;                 // [nc][B][H]

    const size_t base_bytes = (size_t)(part - ws) * sizeof(float);
    int nc = 1;
    for (int c = 32; c >= 1; c >>= 1) {
        if (base_bytes + (size_t)c * B * H * sizeof(float) <= ws_size) { nc = c; break; }
    }
    const int mchunk = M / nc;

    hipLaunchKernelGGL(k_prep, dim3(B), dim3(128), 0, stream,
                       ts, inp, w_t, b_t, Wq, Wk, Wv, qt, vh);
    // pass 1: softmax stats (no scale)
    hipLaunchKernelGGL(k_stats, dim3(B / 128, SC), dim3(256), 0, stream,
                       memory, qt, 1.0f, pmax, psum);
    hipLaunchKernelGGL(k_combine, dim3(B / 256), dim3(256), 0, stream, pmax, psum, gmax, ginv);
    // memory update + L2 normalize
    hipLaunchKernelGGL(k_update, dim3(M / 64), dim3(256), 0, stream,
                       memory, qt, vh, gmax, ginv, memw);
    // pass 2: softmax stats (scaled)
    hipLaunchKernelGGL(k_stats, dim3(B / 128, SC), dim3(256), 0, stream,
                       memw, qt, 0.08838834764831845f, pmax, psum);
    hipLaunchKernelGGL(k_combine, dim3(B / 256), dim3(256), 0, stream, pmax, psum, gmax, ginv);
    // attention read
    hipLaunchKernelGGL(k_read, dim3(B / 64, nc), dim3(256), 0, stream,
                       memw, qt, gmax, ginv, part, mchunk);
    hipLaunchKernelGGL(k_reduce, dim3(B * H / 256), dim3(256), 0, stream, part, out, nc);
}

// Round 3
// 2834.958 us; speedup vs baseline: 3.3599x; 3.1680x over previous
//
#include <hip/hip_runtime.h>
#include <math.h>

#define B 2048
#define M 65536
#define H 128
#define TDIM 128
#define IDIM 256
#define SC 32            // stats chunks over M
#define SCALE2 0.08838834764831845f

typedef short bf8 __attribute__((ext_vector_type(8)));
typedef float f32x4 __attribute__((ext_vector_type(4)));
#define MFMA __builtin_amdgcn_mfma_f32_16x16x32_bf16

__device__ inline unsigned short f2bf(float x) {
    unsigned int u = __float_as_uint(x);
    u += 0x7FFF + ((u >> 16) & 1);
    return (unsigned short)(u >> 16);
}
__device__ inline float bf2f(unsigned short h) {
    return __uint_as_float(((unsigned int)h) << 16);
}
__device__ inline void split2(float x, unsigned short* hi, unsigned short* lo) {
    unsigned short h = f2bf(x);
    *hi = h;
    *lo = f2bf(x - bf2f(h));
}
__device__ inline bf8 ldb(const unsigned short* p) { return *(const bf8*)p; }

// ---------------- K1: prep: qt = ((cos-enc)@Wq^T)@Wk -> bf16 hi/lo; vh fp32 --
__global__ __launch_bounds__(128) void k_prep(const float* __restrict__ ts,
        const float* __restrict__ inp, const float* __restrict__ w_t,
        const float* __restrict__ b_t, const float* __restrict__ Wq,
        const float* __restrict__ Wk, const float* __restrict__ Wv,
        unsigned short* __restrict__ qt_hi, unsigned short* __restrict__ qt_lo,
        float* __restrict__ vh) {
    __shared__ float temb[TDIM];
    __shared__ float qh[H];
    const int b = blockIdx.x, t = threadIdx.x;
    temb[t] = cosf(ts[b] * w_t[t] + b_t[t]);
    __syncthreads();
    float s = 0.f;
    for (int k = 0; k < TDIM; k++) s += temb[k] * Wq[t * TDIM + k];
    qh[t] = s;
    __syncthreads();
    float s2 = 0.f;
    for (int j = 0; j < H; j++) s2 += qh[j] * Wk[j * H + t];
    unsigned short h, l;
    split2(s2, &h, &l);
    qt_hi[b * H + t] = h; qt_lo[b * H + t] = l;
    float s3 = 0.f;
    for (int i = 0; i < IDIM; i++) s3 += inp[b * IDIM + i] * Wv[t * IDIM + i];
    vh[b * H + t] = s3;
}

// ---------------- K2: split memory -> bf16 hi/lo -----------------------------
__global__ __launch_bounds__(256) void k_splitmem(const float* __restrict__ x,
        unsigned short* __restrict__ hi, unsigned short* __restrict__ lo, int n) {
    int i = blockIdx.x * 256 + threadIdx.x;
    const int stride = gridDim.x * 256;
    for (; i < n; i += stride) {
        unsigned short h, l;
        split2(x[i], &h, &l);
        hi[i] = h; lo[i] = l;
    }
}

// ---------------- K3: vh [B][H] -> vhT hi/lo [H][B] --------------------------
__global__ __launch_bounds__(256) void k_tx(const float* __restrict__ vh,
        unsigned short* __restrict__ vhT_hi, unsigned short* __restrict__ vhT_lo) {
    const int d = blockIdx.x;
    const int b = blockIdx.y * 256 + threadIdx.x;
    unsigned short h, l;
    split2(vh[b * H + d], &h, &l);
    vhT_hi[d * B + b] = h; vhT_lo[d * B + b] = l;
}

// ---------------- K4/K7: MFMA stats: per-(16b, chunk) deferred-max sumexp ----
__global__ __launch_bounds__(256) void k_stats(const unsigned short* __restrict__ src_hi,
        const unsigned short* __restrict__ src_lo,
        const unsigned short* __restrict__ qt_hi, const unsigned short* __restrict__ qt_lo,
        float scale, int mchunk,
        float* __restrict__ pmax, float* __restrict__ psum) {
    const int tid = threadIdx.x;
    const int w = tid >> 6, l = tid & 63;
    const int lr = l & 15, g = l >> 4;
    const int brow = blockIdx.x * 64 + w * 16;
    const int m0b = blockIdx.y * mchunk;
    bf8 qh[4], ql[4];
#pragma unroll
    for (int kk = 0; kk < 4; kk++) {
        qh[kk] = ldb(qt_hi + (brow + lr) * H + kk * 32 + g * 8);
        ql[kk] = ldb(qt_lo + (brow + lr) * H + kk * 32 + g * 8);
    }
    float mb[4] = {-INFINITY, -INFINITY, -INFINITY, -INFINITY};
    float sm[4] = {0.f, 0.f, 0.f, 0.f};
    for (int m0 = m0b; m0 < m0b + mchunk; m0 += 32) {
        f32x4 c0 = {0.f, 0.f, 0.f, 0.f}, c1 = {0.f, 0.f, 0.f, 0.f};
#pragma unroll
        for (int kk = 0; kk < 4; kk++) {
            const int o0 = (m0 + lr) * H + kk * 32 + g * 8;
            const int o1 = o0 + 16 * H;
            bf8 b0h = ldb(src_hi + o0), b0l = ldb(src_lo + o0);
            bf8 b1h = ldb(src_hi + o1), b1l = ldb(src_lo + o1);
            c0 = MFMA(qh[kk], b0h, c0, 0, 0, 0);
            c0 = MFMA(qh[kk], b0l, c0, 0, 0, 0);
            c0 = MFMA(ql[kk], b0h, c0, 0, 0, 0);
            c1 = MFMA(qh[kk], b1h, c1, 0, 0, 0);
            c1 = MFMA(qh[kk], b1l, c1, 0, 0, 0);
            c1 = MFMA(ql[kk], b1h, c1, 0, 0, 0);
        }
        float s0[4], s1[4], dm = -INFINITY;
#pragma unroll
        for (int r = 0; r < 4; r++) {
            s0[r] = c0[r] * scale; s1[r] = c1[r] * scale;
            dm = fmaxf(dm, fmaxf(s0[r] - mb[r], s1[r] - mb[r]));
        }
        if (__any(dm > 8.f)) {
#pragma unroll
            for (int r = 0; r < 4; r++) {
                float mx = fmaxf(mb[r], fmaxf(s0[r], s1[r]));
                sm[r] = sm[r] * __expf(mb[r] - mx) + __expf(s0[r] - mx) + __expf(s1[r] - mx);
                mb[r] = mx;
            }
        } else {
#pragma unroll
            for (int r = 0; r < 4; r++)
                sm[r] += __expf(s0[r] - mb[r]) + __expf(s1[r] - mb[r]);
        }
    }
#pragma unroll
    for (int r = 0; r < 4; r++) {
#pragma unroll
        for (int x = 1; x < 16; x <<= 1) {
            float om = __shfl_xor(mb[r], x);
            float os = __shfl_xor(sm[r], x);
            float nm = fmaxf(mb[r], om);
            sm[r] = sm[r] * __expf(mb[r] - nm) + os * __expf(om - nm);
            mb[r] = nm;
        }
    }
    if (lr == 0) {
#pragma unroll
        for (int r = 0; r < 4; r++) {
            const int row = brow + g * 4 + r;
            pmax[row * SC + blockIdx.y] = mb[r];
            psum[row * SC + blockIdx.y] = sm[r];
        }
    }
}

// ---------------- K5/K8: combine chunk stats ---------------------------------
__global__ __launch_bounds__(256) void k_combine(const float* __restrict__ pmax,
        const float* __restrict__ psum, float* __restrict__ gmax,
        float* __restrict__ ginv) {
    const int b = blockIdx.x * 256 + threadIdx.x;
    float mx = -INFINITY;
    for (int c = 0; c < SC; c++) mx = fmaxf(mx, pmax[b * SC + c]);
    float z = 0.f;
    for (int c = 0; c < SC; c++) z += psum[b * SC + c] * __expf(pmax[b * SC + c] - mx);
    gmax[b] = mx;
    ginv[b] = 1.f / z;
}

// ---------------- K6: update: memw = normalize(memory + P1^T @ vh) -----------
__global__ __launch_bounds__(256) void k_update(const float* __restrict__ memory,
        const unsigned short* __restrict__ mem_hi, const unsigned short* __restrict__ mem_lo,
        const unsigned short* __restrict__ qt_hi, const unsigned short* __restrict__ qt_lo,
        const unsigned short* __restrict__ vhT_hi, const unsigned short* __restrict__ vhT_lo,
        const float* __restrict__ gmax, const float* __restrict__ ginv,
        unsigned short* __restrict__ memw_hi, unsigned short* __restrict__ memw_lo,
        unsigned short* __restrict__ memwT_hi, unsigned short* __restrict__ memwT_lo) {
    __shared__ unsigned short lds[18432];  // 36 KB: P-tiles (front 8KB) / epilogue transpose
    const int tid = threadIdx.x;
    const int w = tid >> 6, l = tid & 63;
    const int lr = l & 15, g = l >> 4;
    const int mrow = blockIdx.x * 64 + w * 16;
    bf8 ah[4], al[4];
#pragma unroll
    for (int kk = 0; kk < 4; kk++) {
        ah[kk] = ldb(mem_hi + (mrow + lr) * H + kk * 32 + g * 8);
        al[kk] = ldb(mem_lo + (mrow + lr) * H + kk * 32 + g * 8);
    }
    f32x4 acc[8];
#pragma unroll
    for (int dt = 0; dt < 8; dt++) acc[dt] = (f32x4){0.f, 0.f, 0.f, 0.f};
    unsigned short* Ph = lds + w * 1024;
    unsigned short* Pl = Ph + 512;
    for (int b0 = 0; b0 < B; b0 += 32) {
        f32x4 c0 = {0.f, 0.f, 0.f, 0.f}, c1 = {0.f, 0.f, 0.f, 0.f};
#pragma unroll
        for (int kk = 0; kk < 4; kk++) {
            const int q0 = (b0 + lr) * H + kk * 32 + g * 8;
            const int q1 = q0 + 16 * H;
            bf8 b0h = ldb(qt_hi + q0), b0l = ldb(qt_lo + q0);
            bf8 b1h = ldb(qt_hi + q1), b1l = ldb(qt_lo + q1);
            c0 = MFMA(ah[kk], b0h, c0, 0, 0, 0);
            c0 = MFMA(ah[kk], b0l, c0, 0, 0, 0);
            c0 = MFMA(al[kk], b0h, c0, 0, 0, 0);
            c1 = MFMA(ah[kk], b1h, c1, 0, 0, 0);
            c1 = MFMA(ah[kk], b1l, c1, 0, 0, 0);
            c1 = MFMA(al[kk], b1h, c1, 0, 0, 0);
        }
        // C: row = m-local (g*4+r), col = b-local (lr / 16+lr)
        const float gm0 = gmax[b0 + lr],       gi0 = ginv[b0 + lr];
        const float gm1 = gmax[b0 + 16 + lr],  gi1 = ginv[b0 + 16 + lr];
#pragma unroll
        for (int r = 0; r < 4; r++) {
            float p0 = __expf(c0[r] - gm0) * gi0;
            float p1 = __expf(c1[r] - gm1) * gi1;
            unsigned short h, lo_;
            split2(p0, &h, &lo_);
            Ph[(g * 4 + r) * 32 + lr] = h;       Pl[(g * 4 + r) * 32 + lr] = lo_;
            split2(p1, &h, &lo_);
            Ph[(g * 4 + r) * 32 + 16 + lr] = h;  Pl[(g * 4 + r) * 32 + 16 + lr] = lo_;
        }
        bf8 pah = *(const bf8*)(Ph + lr * 32 + g * 8);
        bf8 pal = *(const bf8*)(Pl + lr * 32 + g * 8);
#pragma unroll
        for (int dt = 0; dt < 8; dt++) {
            const int vo = (dt * 16 + lr) * B + b0 + g * 8;
            bf8 vhh = ldb(vhT_hi + vo), vhl = ldb(vhT_lo + vo);
            acc[dt] = MFMA(pah, vhh, acc[dt], 0, 0, 0);
            acc[dt] = MFMA(pal, vhh, acc[dt], 0, 0, 0);
            acc[dt] = MFMA(pah, vhl, acc[dt], 0, 0, 0);
        }
    }
    __syncthreads();
    // epilogue: new = memory + acc, L2-normalize rows, write memw + LDS-transpose
    float nv[8][4];
    float n2[4] = {0.f, 0.f, 0.f, 0.f};
#pragma unroll
    for (int dt = 0; dt < 8; dt++) {
#pragma unroll
        for (int r = 0; r < 4; r++) {
            float v = acc[dt][r] + memory[(mrow + g * 4 + r) * H + dt * 16 + lr];
            nv[dt][r] = v;
            n2[r] += v * v;
        }
    }
#pragma unroll
    for (int r = 0; r < 4; r++) {
#pragma unroll
        for (int x = 1; x < 16; x <<= 1) n2[r] += __shfl_xor(n2[r], x);
        n2[r] = 1.f / fmaxf(sqrtf(n2[r]), 1e-12f);
    }
#pragma unroll
    for (int dt = 0; dt < 8; dt++) {
#pragma unroll
        for (int r = 0; r < 4; r++) {
            float v = nv[dt][r] * n2[r];
            unsigned short h, lo_;
            split2(v, &h, &lo_);
            const int mr = mrow + g * 4 + r;
            const int d = dt * 16 + lr;
            memw_hi[mr * H + d] = h;
            memw_lo[mr * H + d] = lo_;
            const int mloc = w * 16 + g * 4 + r;
            lds[d * 72 + mloc] = h;
            lds[9216 + d * 72 + mloc] = lo_;
        }
    }
    __syncthreads();
    {
        const int d = tid & 127;
        const unsigned short* row = lds + (tid >> 7) * 9216 + d * 72;
        unsigned short* dst = ((tid >> 7) ? memwT_lo : memwT_hi) + d * M + blockIdx.x * 64;
        const uint4* rs = (const uint4*)row;
        uint4* dq = (uint4*)dst;
#pragma unroll
        for (int j = 0; j < 8; j++) dq[j] = rs[j];
    }
}

// ---------------- K9: read: rpart[chunk] = softmax2 @ memw -------------------
__global__ __launch_bounds__(256) void k_read(const unsigned short* __restrict__ memw_hi,
        const unsigned short* __restrict__ memw_lo,
        const unsigned short* __restrict__ memwT_hi, const unsigned short* __restrict__ memwT_lo,
        const unsigned short* __restrict__ qt_hi, const unsigned short* __restrict__ qt_lo,
        const float* __restrict__ gmax, const float* __restrict__ ginv,
        float* __restrict__ rpart, int mchunk) {
    __shared__ unsigned short lds[4096];
    const int tid = threadIdx.x;
    const int w = tid >> 6, l = tid & 63;
    const int lr = l & 15, g = l >> 4;
    const int brow0 = blockIdx.x * 64 + w * 16;
    const int m0b = blockIdx.y * mchunk;
    bf8 qh[4], ql[4];
#pragma unroll
    for (int kk = 0; kk < 4; kk++) {
        qh[kk] = ldb(qt_hi + (brow0 + lr) * H + kk * 32 + g * 8);
        ql[kk] = ldb(qt_lo + (brow0 + lr) * H + kk * 32 + g * 8);
    }
    float gm[4], gi[4];
#pragma unroll
    for (int r = 0; r < 4; r++) {
        gm[r] = gmax[brow0 + g * 4 + r];
        gi[r] = ginv[brow0 + g * 4 + r];
    }
    f32x4 acc[8];
#pragma unroll
    for (int dt = 0; dt < 8; dt++) acc[dt] = (f32x4){0.f, 0.f, 0.f, 0.f};
    unsigned short* Ph = lds + w * 1024;
    unsigned short* Pl = Ph + 512;
    for (int m0 = m0b; m0 < m0b + mchunk; m0 += 32) {
        f32x4 c0 = {0.f, 0.f, 0.f, 0.f}, c1 = {0.f, 0.f, 0.f, 0.f};
#pragma unroll
        for (int kk = 0; kk < 4; kk++) {
            const int o0 = (m0 + lr) * H + kk * 32 + g * 8;
            const int o1 = o0 + 16 * H;
            bf8 b0h = ldb(memw_hi + o0), b0l = ldb(memw_lo + o0);
            bf8 b1h = ldb(memw_hi + o1), b1l = ldb(memw_lo + o1);
            c0 = MFMA(qh[kk], b0h, c0, 0, 0, 0);
            c0 = MFMA(qh[kk], b0l, c0, 0, 0, 0);
            c0 = MFMA(ql[kk], b0h, c0, 0, 0, 0);
            c1 = MFMA(qh[kk], b1h, c1, 0, 0, 0);
            c1 = MFMA(qh[kk], b1l, c1, 0, 0, 0);
            c1 = MFMA(ql[kk], b1h, c1, 0, 0, 0);
        }
        // C: row = b-local (g*4+r), col = m-local (lr / 16+lr). P2 -> LDS [16b][32m]
#pragma unroll
        for (int r = 0; r < 4; r++) {
            float p0 = __expf(c0[r] * SCALE2 - gm[r]) * gi[r];
            float p1 = __expf(c1[r] * SCALE2 - gm[r]) * gi[r];
            unsigned short h, lo_;
            split2(p0, &h, &lo_);
            Ph[(g * 4 + r) * 32 + lr] = h;       Pl[(g * 4 + r) * 32 + lr] = lo_;
            split2(p1, &h, &lo_);
            Ph[(g * 4 + r) * 32 + 16 + lr] = h;  Pl[(g * 4 + r) * 32 + 16 + lr] = lo_;
        }
        bf8 pah = *(const bf8*)(Ph + lr * 32 + g * 8);
        bf8 pal = *(const bf8*)(Pl + lr * 32 + g * 8);
#pragma unroll
        for (int dt = 0; dt < 8; dt++) {
            const int to = (dt * 16 + lr) * M + m0 + g * 8;
            bf8 th = ldb(memwT_hi + to), tl = ldb(memwT_lo + to);
            acc[dt] = MFMA(pah, th, acc[dt], 0, 0, 0);
            acc[dt] = MFMA(pal, th, acc[dt], 0, 0, 0);
            acc[dt] = MFMA(pah, tl, acc[dt], 0, 0, 0);
        }
    }
    float* rp = rpart + (size_t)blockIdx.y * B * H;
#pragma unroll
    for (int dt = 0; dt < 8; dt++) {
#pragma unroll
        for (int r = 0; r < 4; r++)
            rp[(brow0 + g * 4 + r) * H + dt * 16 + lr] = acc[dt][r];
    }
}

// ---------------- K10: reduce partials -> out --------------------------------
__global__ __launch_bounds__(256) void k_reduce(const float* __restrict__ part,
        float* __restrict__ out, int nc) {
    const int i = blockIdx.x * 256 + threadIdx.x;
    float s = 0.f;
    for (int c = 0; c < nc; c++) s += part[(size_t)c * B * H + i];
    out[i] = s;
}

extern "C" void kernel_launch(void* const* d_in, const int* in_sizes, int n_in,
                              void* d_out, int out_size, void* d_ws, size_t ws_size,
                              hipStream_t stream) {
    const float* ts     = (const float*)d_in[0];
    const float* inp    = (const float*)d_in[1];
    const float* memory = (const float*)d_in[2];
    const float* w_t    = (const float*)d_in[3];
    const float* b_t    = (const float*)d_in[4];
    const float* Wq     = (const float*)d_in[5];
    const float* Wk     = (const float*)d_in[6];
    const float* Wv     = (const float*)d_in[7];
    float* out = (float*)d_out;

    char* p = (char*)d_ws;
    auto alloc = [&](size_t bytes) { char* r = p; p += (bytes + 255) & ~(size_t)255; return r; };
    unsigned short* mem_hi  = (unsigned short*)alloc((size_t)M * H * 2);
    unsigned short* mem_lo  = (unsigned short*)alloc((size_t)M * H * 2);
    unsigned short* memw_hi = (unsigned short*)alloc((size_t)M * H * 2);
    unsigned short* memw_lo = (unsigned short*)alloc((size_t)M * H * 2);
    unsigned short* memwT_hi= (unsigned short*)alloc((size_t)M * H * 2);
    unsigned short* memwT_lo= (unsigned short*)alloc((size_t)M * H * 2);
    unsigned short* qt_hi   = (unsigned short*)alloc((size_t)B * H * 2);
    unsigned short* qt_lo   = (unsigned short*)alloc((size_t)B * H * 2);
    unsigned short* vhT_hi  = (unsigned short*)alloc((size_t)B * H * 2);
    unsigned short* vhT_lo  = (unsigned short*)alloc((size_t)B * H * 2);
    float* vh   = (float*)alloc((size_t)B * H * 4);
    float* pmax = (float*)alloc((size_t)B * SC * 4);
    float* psum = (float*)alloc((size_t)B * SC * 4);
    float* gmax = (float*)alloc((size_t)B * 4);
    float* ginv = (float*)alloc((size_t)B * 4);
    float* rpart = (float*)p;
    size_t remain = ws_size - (size_t)(p - (char*)d_ws);
    int NC = 1;
    for (int c = 16; c >= 1; c >>= 1) {
        if ((size_t)c * B * H * 4 <= remain) { NC = c; break; }
    }
    const int mchunk_r = M / NC;

    hipLaunchKernelGGL(k_prep, dim3(B), dim3(128), 0, stream,
                       ts, inp, w_t, b_t, Wq, Wk, Wv, qt_hi, qt_lo, vh);
    hipLaunchKernelGGL(k_splitmem, dim3(2048), dim3(256), 0, stream,
                       memory, mem_hi, mem_lo, M * H);
    hipLaunchKernelGGL(k_tx, dim3(H, B / 256), dim3(256), 0, stream, vh, vhT_hi, vhT_lo);
    // pass 1 stats (scale = 1)
    hipLaunchKernelGGL(k_stats, dim3(B / 64, SC), dim3(256), 0, stream,
                       mem_hi, mem_lo, qt_hi, qt_lo, 1.0f, M / SC, pmax, psum);
    hipLaunchKernelGGL(k_combine, dim3(B / 256), dim3(256), 0, stream, pmax, psum, gmax, ginv);
    // update
    hipLaunchKernelGGL(k_update, dim3(M / 64), dim3(256), 0, stream,
                       memory, mem_hi, mem_lo, qt_hi, qt_lo, vhT_hi, vhT_lo,
                       gmax, ginv, memw_hi, memw_lo, memwT_hi, memwT_lo);
    // pass 2 stats (scale = 1/sqrt(128))
    hipLaunchKernelGGL(k_stats, dim3(B / 64, SC), dim3(256), 0, stream,
                       memw_hi, memw_lo, qt_hi, qt_lo, SCALE2, M / SC, pmax, psum);
    hipLaunchKernelGGL(k_combine, dim3(B / 256), dim3(256), 0, stream, pmax, psum, gmax, ginv);
    // read
    hipLaunchKernelGGL(k_read, dim3(B / 64, NC), dim3(256), 0, stream,
                       memw_hi, memw_lo, memwT_hi, memwT_lo, qt_hi, qt_lo,
                       gmax, ginv, rpart, mchunk_r);
    hipLaunchKernelGGL(k_reduce, dim3(B * H / 256), dim3(256), 0, stream, rpart, out, NC);
}

// Round 4
// 2447.254 us; speedup vs baseline: 3.8922x; 1.1584x over previous
//
#include <hip/hip_runtime.h>
#include <math.h>

#define B 2048
#define M 65536
#define H 128
#define TDIM 128
#define IDIM 256
#define SC 32            // stats-1 chunks over M
#define SCALE2 0.08838834764831845f

typedef short bf8 __attribute__((ext_vector_type(8)));
typedef float f32x4 __attribute__((ext_vector_type(4)));
#define MFMA __builtin_amdgcn_mfma_f32_16x16x32_bf16
typedef unsigned short us;

__device__ inline us f2bf(float x) {
    unsigned u = __float_as_uint(x);
    u += 0x7FFF + ((u >> 16) & 1);
    return (us)(u >> 16);
}
__device__ inline float bf2f(us h) { return __uint_as_float(((unsigned)h) << 16); }
__device__ inline void split2(float x, us* hi, us* lo) {
    us h = f2bf(x); *hi = h; *lo = f2bf(x - bf2f(h));
}
__device__ inline bf8 ldb(const us* p) { return *(const bf8*)p; }

// ---------------- K1: prep: qt = ((cos-enc)@Wq^T)@Wk -> bf16 hi/lo; vh fp32 --
__global__ __launch_bounds__(128) void k_prep(const float* __restrict__ ts,
        const float* __restrict__ inp, const float* __restrict__ w_t,
        const float* __restrict__ b_t, const float* __restrict__ Wq,
        const float* __restrict__ Wk, const float* __restrict__ Wv,
        us* __restrict__ qt_hi, us* __restrict__ qt_lo, float* __restrict__ vh) {
    __shared__ float temb[TDIM];
    __shared__ float qh[H];
    const int b = blockIdx.x, t = threadIdx.x;
    temb[t] = cosf(ts[b] * w_t[t] + b_t[t]);
    __syncthreads();
    float s = 0.f;
    for (int k = 0; k < TDIM; k++) s += temb[k] * Wq[t * TDIM + k];
    qh[t] = s;
    __syncthreads();
    float s2 = 0.f;
    for (int j = 0; j < H; j++) s2 += qh[j] * Wk[j * H + t];
    us h, l;
    split2(s2, &h, &l);
    qt_hi[b * H + t] = h; qt_lo[b * H + t] = l;
    float s3 = 0.f;
    for (int i = 0; i < IDIM; i++) s3 += inp[b * IDIM + i] * Wv[t * IDIM + i];
    vh[b * H + t] = s3;
}

// ---------------- K2: split memory -> bf16 hi/lo -----------------------------
__global__ __launch_bounds__(256) void k_splitmem(const float* __restrict__ x,
        us* __restrict__ hi, us* __restrict__ lo, int n) {
    int i = blockIdx.x * 256 + threadIdx.x;
    const int stride = gridDim.x * 256;
    for (; i < n; i += stride) {
        us h, l;
        split2(x[i], &h, &l);
        hi[i] = h; lo[i] = l;
    }
}

// ---------------- K3: vh [B][H] -> vhT hi/lo [H][B] --------------------------
__global__ __launch_bounds__(256) void k_tx(const float* __restrict__ vh,
        us* __restrict__ vhT_hi, us* __restrict__ vhT_lo) {
    const int d = blockIdx.x;
    const int b = blockIdx.y * 256 + threadIdx.x;
    us h, l;
    split2(vh[b * H + d], &h, &l);
    vhT_hi[d * B + b] = h; vhT_lo[d * B + b] = l;
}

// ---------------- K4: stats pass 1 (deferred-max sumexp over m) --------------
// A = qt (rows b), B = mem (cols m): C[b][m], lane: b=g*4+r, m=lr.
__global__ __launch_bounds__(256) void k_stats(const us* __restrict__ src_hi,
        const us* __restrict__ src_lo,
        const us* __restrict__ qt_hi, const us* __restrict__ qt_lo,
        int mchunk, float* __restrict__ pmax, float* __restrict__ psum) {
    const int tid = threadIdx.x;
    const int w = tid >> 6, l = tid & 63;
    const int lr = l & 15, g = l >> 4;
    const int brow = blockIdx.x * 64 + w * 16;
    const int m0b = blockIdx.y * mchunk;
    bf8 qh[4], ql[4];
#pragma unroll
    for (int kk = 0; kk < 4; kk++) {
        qh[kk] = ldb(qt_hi + (brow + lr) * H + kk * 32 + g * 8);
        ql[kk] = ldb(qt_lo + (brow + lr) * H + kk * 32 + g * 8);
    }
    float mb[4] = {-INFINITY, -INFINITY, -INFINITY, -INFINITY};
    float sm[4] = {0.f, 0.f, 0.f, 0.f};
    for (int m0 = m0b; m0 < m0b + mchunk; m0 += 32) {
        f32x4 c0 = {0.f, 0.f, 0.f, 0.f}, c1 = {0.f, 0.f, 0.f, 0.f};
#pragma unroll
        for (int kk = 0; kk < 4; kk++) {
            const int o0 = (m0 + lr) * H + kk * 32 + g * 8;
            const int o1 = o0 + 16 * H;
            bf8 b0h = ldb(src_hi + o0), b0l = ldb(src_lo + o0);
            bf8 b1h = ldb(src_hi + o1), b1l = ldb(src_lo + o1);
            c0 = MFMA(qh[kk], b0h, c0, 0, 0, 0);
            c0 = MFMA(qh[kk], b0l, c0, 0, 0, 0);
            c0 = MFMA(ql[kk], b0h, c0, 0, 0, 0);
            c1 = MFMA(qh[kk], b1h, c1, 0, 0, 0);
            c1 = MFMA(qh[kk], b1l, c1, 0, 0, 0);
            c1 = MFMA(ql[kk], b1h, c1, 0, 0, 0);
        }
        float s0[4], s1[4], dm = -INFINITY;
#pragma unroll
        for (int r = 0; r < 4; r++) {
            s0[r] = c0[r]; s1[r] = c1[r];
            dm = fmaxf(dm, fmaxf(s0[r] - mb[r], s1[r] - mb[r]));
        }
        if (__any(dm > 8.f)) {
#pragma unroll
            for (int r = 0; r < 4; r++) {
                float mx = fmaxf(mb[r], fmaxf(s0[r], s1[r]));
                sm[r] = sm[r] * __expf(mb[r] - mx) + __expf(s0[r] - mx) + __expf(s1[r] - mx);
                mb[r] = mx;
            }
        } else {
#pragma unroll
            for (int r = 0; r < 4; r++)
                sm[r] += __expf(s0[r] - mb[r]) + __expf(s1[r] - mb[r]);
        }
    }
#pragma unroll
    for (int r = 0; r < 4; r++) {
#pragma unroll
        for (int x = 1; x < 16; x <<= 1) {
            float om = __shfl_xor(mb[r], x);
            float os = __shfl_xor(sm[r], x);
            float nm = fmaxf(mb[r], om);
            sm[r] = sm[r] * __expf(mb[r] - nm) + os * __expf(om - nm);
            mb[r] = nm;
        }
    }
    if (lr == 0) {
#pragma unroll
        for (int r = 0; r < 4; r++) {
            const int row = brow + g * 4 + r;
            pmax[row * SC + blockIdx.y] = mb[r];
            psum[row * SC + blockIdx.y] = sm[r];
        }
    }
}

// ---------------- K5: combine -> ffac[b] = exp(-gmax)/Z ----------------------
__global__ __launch_bounds__(256) void k_combine1(const float* __restrict__ pmax,
        const float* __restrict__ psum, float* __restrict__ ffac) {
    const int b = blockIdx.x * 256 + threadIdx.x;
    float mx = -INFINITY;
    for (int c = 0; c < SC; c++) mx = fmaxf(mx, pmax[b * SC + c]);
    float z = 0.f;
    for (int c = 0; c < SC; c++) z += psum[b * SC + c] * __expf(pmax[b * SC + c] - mx);
    ffac[b] = __expf(-mx) / z;
}

// ---------------- K6: update: memw = normalize(memory + P1^T @ vh) -----------
// QK swapped: A=qt (rows b), B=mem (cols m) -> C[b][m]; lane (b=g*4+r, m=lr).
// LDS [m][b]: write addr lr*32+g*4 (contig), read A-frag at lr*32+g*8 (contig).
__global__ __launch_bounds__(256) void k_update(const float* __restrict__ memory,
        const us* __restrict__ mem_hi, const us* __restrict__ mem_lo,
        const us* __restrict__ qt_hi, const us* __restrict__ qt_lo,
        const us* __restrict__ vhT_hi, const us* __restrict__ vhT_lo,
        const float* __restrict__ ffac,
        us* __restrict__ memw_hi, us* __restrict__ memw_lo,
        us* __restrict__ memwT_hi, us* __restrict__ memwT_lo) {
    __shared__ us lds[9216];  // 18KB: 4x1KB wave-private P + epilogue [128][72]
    const int tid = threadIdx.x;
    const int w = tid >> 6, l = tid & 63;
    const int lr = l & 15, g = l >> 4;
    const int mrow = blockIdx.x * 64 + w * 16;
    bf8 bh[4], blo[4];
#pragma unroll
    for (int kk = 0; kk < 4; kk++) {
        bh[kk]  = ldb(mem_hi + (mrow + lr) * H + kk * 32 + g * 8);
        blo[kk] = ldb(mem_lo + (mrow + lr) * H + kk * 32 + g * 8);
    }
    f32x4 acc[8];
#pragma unroll
    for (int dt = 0; dt < 8; dt++) acc[dt] = (f32x4){0.f, 0.f, 0.f, 0.f};
    us* Ph = lds + w * 1024;
    us* Pl = Ph + 512;
    for (int b0 = 0; b0 < B; b0 += 32) {
        f32x4 c0 = {0.f, 0.f, 0.f, 0.f}, c1 = {0.f, 0.f, 0.f, 0.f};
#pragma unroll
        for (int kk = 0; kk < 4; kk++) {
            const int q0 = (b0 + lr) * H + kk * 32 + g * 8;
            const int q1 = q0 + 16 * H;
            bf8 a0h = ldb(qt_hi + q0), a0l = ldb(qt_lo + q0);
            bf8 a1h = ldb(qt_hi + q1), a1l = ldb(qt_lo + q1);
            c0 = MFMA(a0h, bh[kk], c0, 0, 0, 0);
            c0 = MFMA(a0l, bh[kk], c0, 0, 0, 0);
            c0 = MFMA(a0h, blo[kk], c0, 0, 0, 0);
            c1 = MFMA(a1h, bh[kk], c1, 0, 0, 0);
            c1 = MFMA(a1l, bh[kk], c1, 0, 0, 0);
            c1 = MFMA(a1h, blo[kk], c1, 0, 0, 0);
        }
        us hh[8], ll[8];
#pragma unroll
        for (int r = 0; r < 4; r++) {
            float p0 = __expf(c0[r]) * ffac[b0 + g * 4 + r];
            float p1 = __expf(c1[r]) * ffac[b0 + 16 + g * 4 + r];
            split2(p0, &hh[r], &ll[r]);
            split2(p1, &hh[4 + r], &ll[4 + r]);
        }
        uint2 v;
        v.x = (unsigned)hh[0] | ((unsigned)hh[1] << 16);
        v.y = (unsigned)hh[2] | ((unsigned)hh[3] << 16);
        *(uint2*)(Ph + lr * 32 + g * 4) = v;
        v.x = (unsigned)hh[4] | ((unsigned)hh[5] << 16);
        v.y = (unsigned)hh[6] | ((unsigned)hh[7] << 16);
        *(uint2*)(Ph + lr * 32 + 16 + g * 4) = v;
        v.x = (unsigned)ll[0] | ((unsigned)ll[1] << 16);
        v.y = (unsigned)ll[2] | ((unsigned)ll[3] << 16);
        *(uint2*)(Pl + lr * 32 + g * 4) = v;
        v.x = (unsigned)ll[4] | ((unsigned)ll[5] << 16);
        v.y = (unsigned)ll[6] | ((unsigned)ll[7] << 16);
        *(uint2*)(Pl + lr * 32 + 16 + g * 4) = v;
        bf8 pah = *(const bf8*)(Ph + lr * 32 + g * 8);
        bf8 pal = *(const bf8*)(Pl + lr * 32 + g * 8);
#pragma unroll
        for (int dt = 0; dt < 8; dt++) {
            const int vo = (dt * 16 + lr) * B + b0 + g * 8;
            bf8 vhh = ldb(vhT_hi + vo), vhl = ldb(vhT_lo + vo);
            acc[dt] = MFMA(pah, vhh, acc[dt], 0, 0, 0);
            acc[dt] = MFMA(pal, vhh, acc[dt], 0, 0, 0);
            acc[dt] = MFMA(pah, vhl, acc[dt], 0, 0, 0);
        }
    }
    // epilogue: new = memory + acc; L2-normalize rows; write memw + memwT
    float nvn[8][4];
    float n2[4] = {0.f, 0.f, 0.f, 0.f};
#pragma unroll
    for (int dt = 0; dt < 8; dt++) {
#pragma unroll
        for (int r = 0; r < 4; r++) {
            float v = acc[dt][r] + memory[(mrow + g * 4 + r) * H + dt * 16 + lr];
            nvn[dt][r] = v;
            n2[r] += v * v;
        }
    }
#pragma unroll
    for (int r = 0; r < 4; r++) {
#pragma unroll
        for (int x = 1; x < 16; x <<= 1) n2[r] += __shfl_xor(n2[r], x);
        n2[r] = 1.f / fmaxf(sqrtf(n2[r]), 1e-12f);
    }
#pragma unroll
    for (int dt = 0; dt < 8; dt++)
#pragma unroll
        for (int r = 0; r < 4; r++) nvn[dt][r] *= n2[r];
    __syncthreads();
    // phase hi
#pragma unroll
    for (int dt = 0; dt < 8; dt++) {
#pragma unroll
        for (int r = 0; r < 4; r++) {
            us h = f2bf(nvn[dt][r]);
            memw_hi[(mrow + g * 4 + r) * H + dt * 16 + lr] = h;
            lds[(dt * 16 + lr) * 72 + w * 16 + g * 4 + r] = h;
        }
    }
    __syncthreads();
    {
        const int d = tid >> 1, seg = tid & 1;
        uint4* dq = (uint4*)(memwT_hi + (size_t)d * M + blockIdx.x * 64 + seg * 32);
        const uint4* src = (const uint4*)(lds + d * 72 + seg * 32);
#pragma unroll
        for (int j = 0; j < 4; j++) dq[j] = src[j];
    }
    __syncthreads();
    // phase lo
#pragma unroll
    for (int dt = 0; dt < 8; dt++) {
#pragma unroll
        for (int r = 0; r < 4; r++) {
            float vv = nvn[dt][r];
            us h = f2bf(vv);
            us lo2 = f2bf(vv - bf2f(h));
            memw_lo[(mrow + g * 4 + r) * H + dt * 16 + lr] = lo2;
            lds[(dt * 16 + lr) * 72 + w * 16 + g * 4 + r] = lo2;
        }
    }
    __syncthreads();
    {
        const int d = tid >> 1, seg = tid & 1;
        uint4* dq = (uint4*)(memwT_lo + (size_t)d * M + blockIdx.x * 64 + seg * 32);
        const uint4* src = (const uint4*)(lds + d * 72 + seg * 32);
#pragma unroll
        for (int j = 0; j < 4; j++) dq[j] = src[j];
    }
}

// ---------------- K7: flash read: fused stats2 + PV over m-chunks ------------
// QK: A=memw (rows m), B=qt (cols b): C[m][b], lane (m=g*4+r, b=lr).
// LDS [b][m]: write lr*32+g*4 contig; PV A-frag P[b=lr][m=g*8..] read contig.
__global__ __launch_bounds__(256) void k_fread(const us* __restrict__ memw_hi,
        const us* __restrict__ memw_lo,
        const us* __restrict__ memwT_hi, const us* __restrict__ memwT_lo,
        const us* __restrict__ qt_hi, const us* __restrict__ qt_lo,
        float* __restrict__ part, float* __restrict__ pmax2,
        float* __restrict__ psum2, int mchunk) {
    __shared__ us lds[4096];
    const int tid = threadIdx.x;
    const int w = tid >> 6, l = tid & 63;
    const int lr = l & 15, g = l >> 4;
    const int brow = blockIdx.x * 64 + w * 16;
    const int m0b = blockIdx.y * mchunk;
    bf8 qh[4], ql[4];
#pragma unroll
    for (int kk = 0; kk < 4; kk++) {
        qh[kk] = ldb(qt_hi + (brow + lr) * H + kk * 32 + g * 8);
        ql[kk] = ldb(qt_lo + (brow + lr) * H + kk * 32 + g * 8);
    }
    f32x4 acc[8];
#pragma unroll
    for (int dt = 0; dt < 8; dt++) acc[dt] = (f32x4){0.f, 0.f, 0.f, 0.f};
    float mb = 0.f, sm = 0.f;  // running stats for b = brow + lr
    us* Ph = lds + w * 1024;
    us* Pl = Ph + 512;
    for (int m0 = m0b; m0 < m0b + mchunk; m0 += 32) {
        f32x4 c0 = {0.f, 0.f, 0.f, 0.f}, c1 = {0.f, 0.f, 0.f, 0.f};
#pragma unroll
        for (int kk = 0; kk < 4; kk++) {
            const int o0 = (m0 + lr) * H + kk * 32 + g * 8;
            const int o1 = o0 + 16 * H;
            bf8 a0h = ldb(memw_hi + o0), a0l = ldb(memw_lo + o0);
            bf8 a1h = ldb(memw_hi + o1), a1l = ldb(memw_lo + o1);
            c0 = MFMA(a0h, qh[kk], c0, 0, 0, 0);
            c0 = MFMA(a0l, qh[kk], c0, 0, 0, 0);
            c0 = MFMA(a0h, ql[kk], c0, 0, 0, 0);
            c1 = MFMA(a1h, qh[kk], c1, 0, 0, 0);
            c1 = MFMA(a1l, qh[kk], c1, 0, 0, 0);
            c1 = MFMA(a1h, ql[kk], c1, 0, 0, 0);
        }
        float s0[4], s1[4], lmax = -INFINITY;
#pragma unroll
        for (int r = 0; r < 4; r++) {
            s0[r] = c0[r] * SCALE2;
            s1[r] = c1[r] * SCALE2;
            lmax = fmaxf(lmax, fmaxf(s0[r], s1[r]));
        }
        lmax = fmaxf(lmax, __shfl_xor(lmax, 16));
        lmax = fmaxf(lmax, __shfl_xor(lmax, 32));
        if (__any(lmax > mb + 8.f)) {
            float nm = fmaxf(mb, lmax);
            float f = __expf(mb - nm);
            sm *= f;
            float fr[4];
#pragma unroll
            for (int r = 0; r < 4; r++) fr[r] = __shfl(f, g * 4 + r);
#pragma unroll
            for (int dt = 0; dt < 8; dt++)
#pragma unroll
                for (int r = 0; r < 4; r++) acc[dt][r] *= fr[r];
            mb = nm;
        }
        us hh[8], ll[8];
#pragma unroll
        for (int r = 0; r < 4; r++) {
            float p0 = __expf(s0[r] - mb);
            float p1 = __expf(s1[r] - mb);
            sm += p0 + p1;
            split2(p0, &hh[r], &ll[r]);
            split2(p1, &hh[4 + r], &ll[4 + r]);
        }
        uint2 v;
        v.x = (unsigned)hh[0] | ((unsigned)hh[1] << 16);
        v.y = (unsigned)hh[2] | ((unsigned)hh[3] << 16);
        *(uint2*)(Ph + lr * 32 + g * 4) = v;
        v.x = (unsigned)hh[4] | ((unsigned)hh[5] << 16);
        v.y = (unsigned)hh[6] | ((unsigned)hh[7] << 16);
        *(uint2*)(Ph + lr * 32 + 16 + g * 4) = v;
        v.x = (unsigned)ll[0] | ((unsigned)ll[1] << 16);
        v.y = (unsigned)ll[2] | ((unsigned)ll[3] << 16);
        *(uint2*)(Pl + lr * 32 + g * 4) = v;
        v.x = (unsigned)ll[4] | ((unsigned)ll[5] << 16);
        v.y = (unsigned)ll[6] | ((unsigned)ll[7] << 16);
        *(uint2*)(Pl + lr * 32 + 16 + g * 4) = v;
        bf8 pah = *(const bf8*)(Ph + lr * 32 + g * 8);
        bf8 pal = *(const bf8*)(Pl + lr * 32 + g * 8);
#pragma unroll
        for (int dt = 0; dt < 8; dt++) {
            const int to = (dt * 16 + lr) * M + m0 + g * 8;
            bf8 th = ldb(memwT_hi + to), tl = ldb(memwT_lo + to);
            acc[dt] = MFMA(pah, th, acc[dt], 0, 0, 0);
            acc[dt] = MFMA(pal, th, acc[dt], 0, 0, 0);
            acc[dt] = MFMA(pah, tl, acc[dt], 0, 0, 0);
        }
    }
    sm += __shfl_xor(sm, 16);
    sm += __shfl_xor(sm, 32);
    if ((l >> 4) == 0) {
        pmax2[(size_t)blockIdx.y * B + brow + lr] = mb;
        psum2[(size_t)blockIdx.y * B + brow + lr] = sm;
    }
    float* rp = part + (size_t)blockIdx.y * B * H;
#pragma unroll
    for (int dt = 0; dt < 8; dt++)
#pragma unroll
        for (int r = 0; r < 4; r++)
            rp[(size_t)(brow + g * 4 + r) * H + dt * 16 + lr] = acc[dt][r];
}

// ---------------- K8: per-b chunk weights ------------------------------------
__global__ __launch_bounds__(256) void k_fstats(const float* __restrict__ pmax2,
        const float* __restrict__ psum2, float* __restrict__ wc, int nc) {
    const int b = blockIdx.x * 256 + threadIdx.x;
    float gm = -INFINITY;
    for (int c = 0; c < nc; c++) gm = fmaxf(gm, pmax2[(size_t)c * B + b]);
    float z = 0.f;
    for (int c = 0; c < nc; c++) z += psum2[(size_t)c * B + b] * __expf(pmax2[(size_t)c * B + b] - gm);
    const float zi = 1.f / z;
    for (int c = 0; c < nc; c++) wc[(size_t)c * B + b] = __expf(pmax2[(size_t)c * B + b] - gm) * zi;
}

// ---------------- K9: weighted combine -> out --------------------------------
__global__ __launch_bounds__(256) void k_fcombine(const float* __restrict__ part,
        const float* __restrict__ wc, float* __restrict__ out, int nc) {
    const int i = blockIdx.x * 256 + threadIdx.x;
    const int b = i >> 7;
    float s = 0.f;
    for (int c = 0; c < nc; c++) s += part[(size_t)c * B * H + i] * wc[(size_t)c * B + b];
    out[i] = s;
}

extern "C" void kernel_launch(void* const* d_in, const int* in_sizes, int n_in,
                              void* d_out, int out_size, void* d_ws, size_t ws_size,
                              hipStream_t stream) {
    const float* ts     = (const float*)d_in[0];
    const float* inp    = (const float*)d_in[1];
    const float* memory = (const float*)d_in[2];
    const float* w_t    = (const float*)d_in[3];
    const float* b_t    = (const float*)d_in[4];
    const float* Wq     = (const float*)d_in[5];
    const float* Wk     = (const float*)d_in[6];
    const float* Wv     = (const float*)d_in[7];
    float* out = (float*)d_out;

    char* p = (char*)d_ws;
    auto alloc = [&](size_t bytes) { char* r = p; p += (bytes + 255) & ~(size_t)255; return r; };
    us* mem_hi   = (us*)alloc((size_t)M * H * 2);
    us* mem_lo   = (us*)alloc((size_t)M * H * 2);
    us* memw_hi  = (us*)alloc((size_t)M * H * 2);
    us* memw_lo  = (us*)alloc((size_t)M * H * 2);
    us* memwT_hi = (us*)alloc((size_t)M * H * 2);
    us* memwT_lo = (us*)alloc((size_t)M * H * 2);
    us* qt_hi    = (us*)alloc((size_t)B * H * 2);
    us* qt_lo    = (us*)alloc((size_t)B * H * 2);
    us* vhT_hi   = (us*)alloc((size_t)B * H * 2);
    us* vhT_lo   = (us*)alloc((size_t)B * H * 2);
    float* vh    = (float*)alloc((size_t)B * H * 4);
    float* pmax  = (float*)alloc((size_t)B * SC * 4);
    float* psum  = (float*)alloc((size_t)B * SC * 4);
    float* ffac  = (float*)alloc((size_t)B * 4);
    size_t remain = ws_size - (size_t)(p - (char*)d_ws);
    int NC = 1;
    for (int c = 32; c >= 1; c >>= 1) {
        size_t need = (size_t)c * B * H * 4 + 3 * (size_t)c * B * 4 + 4096;
        if (need <= remain) { NC = c; break; }
    }
    float* pmax2 = (float*)alloc((size_t)NC * B * 4);
    float* psum2 = (float*)alloc((size_t)NC * B * 4);
    float* wcb   = (float*)alloc((size_t)NC * B * 4);
    float* part  = (float*)alloc((size_t)NC * B * H * 4);
    const int mchunk = M / NC;

    hipLaunchKernelGGL(k_prep, dim3(B), dim3(128), 0, stream,
                       ts, inp, w_t, b_t, Wq, Wk, Wv, qt_hi, qt_lo, vh);
    hipLaunchKernelGGL(k_splitmem, dim3(2048), dim3(256), 0, stream,
                       memory, mem_hi, mem_lo, M * H);
    hipLaunchKernelGGL(k_tx, dim3(H, B / 256), dim3(256), 0, stream, vh, vhT_hi, vhT_lo);
    hipLaunchKernelGGL(k_stats, dim3(B / 64, SC), dim3(256), 0, stream,
                       mem_hi, mem_lo, qt_hi, qt_lo, M / SC, pmax, psum);
    hipLaunchKernelGGL(k_combine1, dim3(B / 256), dim3(256), 0, stream, pmax, psum, ffac);
    hipLaunchKernelGGL(k_update, dim3(M / 64), dim3(256), 0, stream,
                       memory, mem_hi, mem_lo, qt_hi, qt_lo, vhT_hi, vhT_lo,
                       ffac, memw_hi, memw_lo, memwT_hi, memwT_lo);
    hipLaunchKernelGGL(k_fread, dim3(B / 64, NC), dim3(256), 0, stream,
                       memw_hi, memw_lo, memwT_hi, memwT_lo, qt_hi, qt_lo,
                       part, pmax2, psum2, mchunk);
    hipLaunchKernelGGL(k_fstats, dim3(B / 256), dim3(256), 0, stream, pmax2, psum2, wcb, NC);
    hipLaunchKernelGGL(k_fcombine, dim3(B * H / 256), dim3(256), 0, stream, part, wcb, out, NC);
}

// Round 6
// 1528.985 us; speedup vs baseline: 6.2298x; 1.6006x over previous
//
#include <hip/hip_runtime.h>
#include <math.h>

#define B 2048
#define M 65536
#define H 128
#define TDIM 128
#define IDIM 256
#define SC 32            // stats-1 chunks over M
#define SCALE2 0.08838834764831845f
#define PST 36           // padded P-tile row stride (us units) -> 72B, bank step 18

typedef short bf8 __attribute__((ext_vector_type(8)));
typedef float f32x4 __attribute__((ext_vector_type(4)));
#define MFMA __builtin_amdgcn_mfma_f32_16x16x32_bf16
typedef unsigned short us;

__device__ inline us f2bf(float x) {
    unsigned u = __float_as_uint(x);
    u += 0x7FFF + ((u >> 16) & 1);
    return (us)(u >> 16);
}
__device__ inline float bf2f(us h) { return __uint_as_float(((unsigned)h) << 16); }
__device__ inline void split2(float x, us* hi, us* lo) {
    us h = f2bf(x); *hi = h; *lo = f2bf(x - bf2f(h));
}
__device__ inline bf8 ldb(const us* p) { return *(const bf8*)p; }

// ---------------- K1: prep: qt = ((cos-enc)@Wq^T)@Wk -> bf16 hi/lo; vh fp32 --
__global__ __launch_bounds__(128) void k_prep(const float* __restrict__ ts,
        const float* __restrict__ inp, const float* __restrict__ w_t,
        const float* __restrict__ b_t, const float* __restrict__ Wq,
        const float* __restrict__ Wk, const float* __restrict__ Wv,
        us* __restrict__ qt_hi, us* __restrict__ qt_lo, float* __restrict__ vh) {
    __shared__ float temb[TDIM];
    __shared__ float qh[H];
    const int b = blockIdx.x, t = threadIdx.x;
    temb[t] = cosf(ts[b] * w_t[t] + b_t[t]);
    __syncthreads();
    float s = 0.f;
    for (int k = 0; k < TDIM; k++) s += temb[k] * Wq[t * TDIM + k];
    qh[t] = s;
    __syncthreads();
    float s2 = 0.f;
    for (int j = 0; j < H; j++) s2 += qh[j] * Wk[j * H + t];
    us h, l;
    split2(s2, &h, &l);
    qt_hi[b * H + t] = h; qt_lo[b * H + t] = l;
    float s3 = 0.f;
    for (int i = 0; i < IDIM; i++) s3 += inp[b * IDIM + i] * Wv[t * IDIM + i];
    vh[b * H + t] = s3;
}

// ---------------- K2: split memory -> bf16 hi/lo -----------------------------
__global__ __launch_bounds__(256) void k_splitmem(const float* __restrict__ x,
        us* __restrict__ hi, us* __restrict__ lo, int n) {
    int i = blockIdx.x * 256 + threadIdx.x;
    const int stride = gridDim.x * 256;
    for (; i < n; i += stride) {
        us h, l;
        split2(x[i], &h, &l);
        hi[i] = h; lo[i] = l;
    }
}

// ---------------- K3: vh [B][H] -> vhT hi/lo [H][B] --------------------------
__global__ __launch_bounds__(256) void k_tx(const float* __restrict__ vh,
        us* __restrict__ vhT_hi, us* __restrict__ vhT_lo) {
    const int d = blockIdx.x;
    const int b = blockIdx.y * 256 + threadIdx.x;
    us h, l;
    split2(vh[b * H + d], &h, &l);
    vhT_hi[d * B + b] = h; vhT_lo[d * B + b] = l;
}

// ---------------- K4: stats pass 1 (deferred-max sumexp over m) --------------
// A=qt (rows b, 32/wave), B=mem (cols m): C[b][m]: row b=g*4+r, col m=lr.
__global__ __launch_bounds__(256) void k_stats(const us* __restrict__ src_hi,
        const us* __restrict__ src_lo,
        const us* __restrict__ qt_hi, const us* __restrict__ qt_lo,
        int mchunk, float* __restrict__ pmax, float* __restrict__ psum) {
    const int tid = threadIdx.x;
    const int w = tid >> 6, l = tid & 63;
    const int lr = l & 15, g = l >> 4;
    const int brow = blockIdx.x * 128 + w * 32;
    const int m0b = blockIdx.y * mchunk;
    bf8 qh[2][4], ql[2][4];
#pragma unroll
    for (int bt = 0; bt < 2; bt++)
#pragma unroll
        for (int kk = 0; kk < 4; kk++) {
            const int o = (brow + bt * 16 + lr) * H + kk * 32 + g * 8;
            qh[bt][kk] = ldb(qt_hi + o);
            ql[bt][kk] = ldb(qt_lo + o);
        }
    float mb[8], sm[8];
#pragma unroll
    for (int i = 0; i < 8; i++) { mb[i] = -INFINITY; sm[i] = 0.f; }
    for (int m0 = m0b; m0 < m0b + mchunk; m0 += 32) {
        f32x4 c[2][2];  // [bt][mt]
#pragma unroll
        for (int bt = 0; bt < 2; bt++)
#pragma unroll
            for (int mt = 0; mt < 2; mt++) c[bt][mt] = (f32x4){0.f, 0.f, 0.f, 0.f};
#pragma unroll
        for (int kk = 0; kk < 4; kk++) {
            const int o0 = (m0 + lr) * H + kk * 32 + g * 8;
            const int o1 = o0 + 16 * H;
            bf8 b0h = ldb(src_hi + o0), b0l = ldb(src_lo + o0);
            bf8 b1h = ldb(src_hi + o1), b1l = ldb(src_lo + o1);
            c[0][0] = MFMA(qh[0][kk], b0h, c[0][0], 0, 0, 0);
            c[0][0] = MFMA(ql[0][kk], b0h, c[0][0], 0, 0, 0);
            c[0][0] = MFMA(qh[0][kk], b0l, c[0][0], 0, 0, 0);
            c[0][1] = MFMA(qh[0][kk], b1h, c[0][1], 0, 0, 0);
            c[0][1] = MFMA(ql[0][kk], b1h, c[0][1], 0, 0, 0);
            c[0][1] = MFMA(qh[0][kk], b1l, c[0][1], 0, 0, 0);
            c[1][0] = MFMA(qh[1][kk], b0h, c[1][0], 0, 0, 0);
            c[1][0] = MFMA(ql[1][kk], b0h, c[1][0], 0, 0, 0);
            c[1][0] = MFMA(qh[1][kk], b0l, c[1][0], 0, 0, 0);
            c[1][1] = MFMA(qh[1][kk], b1h, c[1][1], 0, 0, 0);
            c[1][1] = MFMA(ql[1][kk], b1h, c[1][1], 0, 0, 0);
            c[1][1] = MFMA(qh[1][kk], b1l, c[1][1], 0, 0, 0);
        }
        float dm = -INFINITY;
#pragma unroll
        for (int bt = 0; bt < 2; bt++)
#pragma unroll
            for (int mt = 0; mt < 2; mt++)
#pragma unroll
                for (int r = 0; r < 4; r++)
                    dm = fmaxf(dm, c[bt][mt][r] - mb[bt * 4 + r]);
        if (__any(dm > 8.f)) {
#pragma unroll
            for (int bt = 0; bt < 2; bt++)
#pragma unroll
                for (int r = 0; r < 4; r++) {
                    const int s = bt * 4 + r;
                    float mx = fmaxf(mb[s], fmaxf(c[bt][0][r], c[bt][1][r]));
                    sm[s] = sm[s] * __expf(mb[s] - mx)
                          + __expf(c[bt][0][r] - mx) + __expf(c[bt][1][r] - mx);
                    mb[s] = mx;
                }
        } else {
#pragma unroll
            for (int bt = 0; bt < 2; bt++)
#pragma unroll
                for (int r = 0; r < 4; r++) {
                    const int s = bt * 4 + r;
                    sm[s] += __expf(c[bt][0][r] - mb[s]) + __expf(c[bt][1][r] - mb[s]);
                }
        }
    }
#pragma unroll
    for (int s = 0; s < 8; s++) {
#pragma unroll
        for (int x = 1; x < 16; x <<= 1) {
            float om = __shfl_xor(mb[s], x);
            float os = __shfl_xor(sm[s], x);
            float nm = fmaxf(mb[s], om);
            sm[s] = sm[s] * __expf(mb[s] - nm) + os * __expf(om - nm);
            mb[s] = nm;
        }
    }
    if (lr == 0) {
#pragma unroll
        for (int bt = 0; bt < 2; bt++)
#pragma unroll
            for (int r = 0; r < 4; r++) {
                const int row = brow + bt * 16 + g * 4 + r;
                pmax[row * SC + blockIdx.y] = mb[bt * 4 + r];
                psum[row * SC + blockIdx.y] = sm[bt * 4 + r];
            }
    }
}

// ---------------- K5: combine -> ffac[b] = exp(-gmax)/Z ----------------------
__global__ __launch_bounds__(256) void k_combine1(const float* __restrict__ pmax,
        const float* __restrict__ psum, float* __restrict__ ffac) {
    const int b = blockIdx.x * 256 + threadIdx.x;
    float mx = -INFINITY;
    for (int c = 0; c < SC; c++) mx = fmaxf(mx, pmax[b * SC + c]);
    float z = 0.f;
    for (int c = 0; c < SC; c++) z += psum[b * SC + c] * __expf(pmax[b * SC + c] - mx);
    ffac[b] = __expf(-mx) / z;
}

// ---------------- K6: update: memw = normalize(memory + P1^T @ vh) -----------
// Wave owns 32 m-rows. QK: A=qt rows b, B=mem cols m -> C[b][m]; P LDS [m][b]
// padded stride 36us. PV: A=P (rows m, K=b), B=vhT.
__global__ __launch_bounds__(256) void k_update(const float* __restrict__ memory,
        const us* __restrict__ mem_hi, const us* __restrict__ mem_lo,
        const us* __restrict__ qt_hi, const us* __restrict__ qt_lo,
        const us* __restrict__ vhT_hi, const us* __restrict__ vhT_lo,
        const float* __restrict__ ffac,
        us* __restrict__ memw_hi, us* __restrict__ memw_lo,
        us* __restrict__ memwT_hi, us* __restrict__ memwT_lo) {
    __shared__ us lds[17408];  // 34.8KB: P (4w x 2304us) / transpose 128x136
    const int tid = threadIdx.x;
    const int w = tid >> 6, l = tid & 63;
    const int lr = l & 15, g = l >> 4;
    const int mrow = blockIdx.x * 128 + w * 32;
    bf8 bh[2][4], bl[2][4];
#pragma unroll
    for (int t = 0; t < 2; t++)
#pragma unroll
        for (int kk = 0; kk < 4; kk++) {
            const int o = (mrow + t * 16 + lr) * H + kk * 32 + g * 8;
            bh[t][kk] = ldb(mem_hi + o);
            bl[t][kk] = ldb(mem_lo + o);
        }
    f32x4 acc[2][8];
#pragma unroll
    for (int t = 0; t < 2; t++)
#pragma unroll
        for (int dt = 0; dt < 8; dt++) acc[t][dt] = (f32x4){0.f, 0.f, 0.f, 0.f};
    us* Ph = lds + w * 2304;
    us* Pl = Ph + 1152;
    for (int b0 = 0; b0 < B; b0 += 32) {
        f32x4 c[2][2];  // [bt][t]
#pragma unroll
        for (int bt = 0; bt < 2; bt++)
#pragma unroll
            for (int t = 0; t < 2; t++) c[bt][t] = (f32x4){0.f, 0.f, 0.f, 0.f};
#pragma unroll
        for (int kk = 0; kk < 4; kk++) {
            const int q0 = (b0 + lr) * H + kk * 32 + g * 8;
            const int q1 = q0 + 16 * H;
            bf8 a0h = ldb(qt_hi + q0), a0l = ldb(qt_lo + q0);
            bf8 a1h = ldb(qt_hi + q1), a1l = ldb(qt_lo + q1);
            c[0][0] = MFMA(a0h, bh[0][kk], c[0][0], 0, 0, 0);
            c[0][0] = MFMA(a0l, bh[0][kk], c[0][0], 0, 0, 0);
            c[0][0] = MFMA(a0h, bl[0][kk], c[0][0], 0, 0, 0);
            c[0][1] = MFMA(a0h, bh[1][kk], c[0][1], 0, 0, 0);
            c[0][1] = MFMA(a0l, bh[1][kk], c[0][1], 0, 0, 0);
            c[0][1] = MFMA(a0h, bl[1][kk], c[0][1], 0, 0, 0);
            c[1][0] = MFMA(a1h, bh[0][kk], c[1][0], 0, 0, 0);
            c[1][0] = MFMA(a1l, bh[0][kk], c[1][0], 0, 0, 0);
            c[1][0] = MFMA(a1h, bl[0][kk], c[1][0], 0, 0, 0);
            c[1][1] = MFMA(a1h, bh[1][kk], c[1][1], 0, 0, 0);
            c[1][1] = MFMA(a1l, bh[1][kk], c[1][1], 0, 0, 0);
            c[1][1] = MFMA(a1h, bl[1][kk], c[1][1], 0, 0, 0);
        }
        const float4 f4a = *(const float4*)(ffac + b0 + g * 4);
        const float4 f4b = *(const float4*)(ffac + b0 + 16 + g * 4);
        float fa[4] = {f4a.x, f4a.y, f4a.z, f4a.w};
        float fb[4] = {f4b.x, f4b.y, f4b.z, f4b.w};
#pragma unroll
        for (int bt = 0; bt < 2; bt++) {
#pragma unroll
            for (int t = 0; t < 2; t++) {
                us hh[4], ll[4];
#pragma unroll
                for (int r = 0; r < 4; r++) {
                    float p = __expf(c[bt][t][r]) * (bt ? fb[r] : fa[r]);
                    split2(p, &hh[r], &ll[r]);
                }
                uint2 v;
                v.x = (unsigned)hh[0] | ((unsigned)hh[1] << 16);
                v.y = (unsigned)hh[2] | ((unsigned)hh[3] << 16);
                *(uint2*)(Ph + (t * 16 + lr) * PST + bt * 16 + g * 4) = v;
                v.x = (unsigned)ll[0] | ((unsigned)ll[1] << 16);
                v.y = (unsigned)ll[2] | ((unsigned)ll[3] << 16);
                *(uint2*)(Pl + (t * 16 + lr) * PST + bt * 16 + g * 4) = v;
            }
        }
        bf8 pah[2], pal[2];
#pragma unroll
        for (int t = 0; t < 2; t++) {
            pah[t] = *(const bf8*)(Ph + (t * 16 + lr) * PST + g * 8);
            pal[t] = *(const bf8*)(Pl + (t * 16 + lr) * PST + g * 8);
        }
#pragma unroll
        for (int dt = 0; dt < 8; dt++) {
            const int vo = (dt * 16 + lr) * B + b0 + g * 8;
            bf8 vhh = ldb(vhT_hi + vo), vhl = ldb(vhT_lo + vo);
            acc[0][dt] = MFMA(pah[0], vhh, acc[0][dt], 0, 0, 0);
            acc[0][dt] = MFMA(pal[0], vhh, acc[0][dt], 0, 0, 0);
            acc[0][dt] = MFMA(pah[0], vhl, acc[0][dt], 0, 0, 0);
            acc[1][dt] = MFMA(pah[1], vhh, acc[1][dt], 0, 0, 0);
            acc[1][dt] = MFMA(pal[1], vhh, acc[1][dt], 0, 0, 0);
            acc[1][dt] = MFMA(pah[1], vhl, acc[1][dt], 0, 0, 0);
        }
    }
    // epilogue: new = memory + acc; L2-normalize rows; write memw + memwT
    float n2[2][4];
#pragma unroll
    for (int t = 0; t < 2; t++)
#pragma unroll
        for (int r = 0; r < 4; r++) n2[t][r] = 0.f;
#pragma unroll
    for (int t = 0; t < 2; t++)
#pragma unroll
        for (int dt = 0; dt < 8; dt++)
#pragma unroll
            for (int r = 0; r < 4; r++) {
                float v = acc[t][dt][r]
                        + memory[(mrow + t * 16 + g * 4 + r) * H + dt * 16 + lr];
                acc[t][dt][r] = v;
                n2[t][r] += v * v;
            }
#pragma unroll
    for (int t = 0; t < 2; t++)
#pragma unroll
        for (int r = 0; r < 4; r++) {
#pragma unroll
            for (int x = 1; x < 16; x <<= 1) n2[t][r] += __shfl_xor(n2[t][r], x);
            n2[t][r] = 1.f / fmaxf(sqrtf(n2[t][r]), 1e-12f);
        }
#pragma unroll
    for (int t = 0; t < 2; t++)
#pragma unroll
        for (int dt = 0; dt < 8; dt++)
#pragma unroll
            for (int r = 0; r < 4; r++) acc[t][dt][r] *= n2[t][r];
    __syncthreads();
    // phase hi
#pragma unroll
    for (int t = 0; t < 2; t++)
#pragma unroll
        for (int dt = 0; dt < 8; dt++)
#pragma unroll
            for (int r = 0; r < 4; r++) {
                us h = f2bf(acc[t][dt][r]);
                memw_hi[(mrow + t * 16 + g * 4 + r) * H + dt * 16 + lr] = h;
                lds[(dt * 16 + lr) * 136 + w * 32 + t * 16 + g * 4 + r] = h;
            }
    __syncthreads();
    {
        // each thread writes 64 us (8 x uint4): full 128 cols = 2 segs x 64
        const int d = tid >> 1, seg = tid & 1;
        uint4* dq = (uint4*)(memwT_hi + (size_t)d * M + blockIdx.x * 128 + seg * 64);
        const uint4* sp = (const uint4*)(lds + d * 136 + seg * 64);
#pragma unroll
        for (int j = 0; j < 8; j++) dq[j] = sp[j];
    }
    __syncthreads();
    // phase lo
#pragma unroll
    for (int t = 0; t < 2; t++)
#pragma unroll
        for (int dt = 0; dt < 8; dt++)
#pragma unroll
            for (int r = 0; r < 4; r++) {
                float vv = acc[t][dt][r];
                us h = f2bf(vv);
                us lo2 = f2bf(vv - bf2f(h));
                memw_lo[(mrow + t * 16 + g * 4 + r) * H + dt * 16 + lr] = lo2;
                lds[(dt * 16 + lr) * 136 + w * 32 + t * 16 + g * 4 + r] = lo2;
            }
    __syncthreads();
    {
        const int d = tid >> 1, seg = tid & 1;
        uint4* dq = (uint4*)(memwT_lo + (size_t)d * M + blockIdx.x * 128 + seg * 64);
        const uint4* sp = (const uint4*)(lds + d * 136 + seg * 64);
#pragma unroll
        for (int j = 0; j < 8; j++) dq[j] = sp[j];
    }
}

// ---------------- K7: flash read: fused stats2 + PV over m-chunks ------------
// Wave owns 32 b-rows. QK: A=memw rows m, B=qt cols b -> C[m][b]; P LDS [b][m]
// stride 36us. PV: A=P (rows b, K=m), B=memwT -> C[b][d].
__global__ __launch_bounds__(256) void k_fread(const us* __restrict__ memw_hi,
        const us* __restrict__ memw_lo,
        const us* __restrict__ memwT_hi, const us* __restrict__ memwT_lo,
        const us* __restrict__ qt_hi, const us* __restrict__ qt_lo,
        float* __restrict__ part, float* __restrict__ pmax2,
        float* __restrict__ psum2, int mchunk) {
    __shared__ us lds[9216];
    const int tid = threadIdx.x;
    const int w = tid >> 6, l = tid & 63;
    const int lr = l & 15, g = l >> 4;
    const int brow = blockIdx.x * 128 + w * 32;
    const int m0b = blockIdx.y * mchunk;
    bf8 qh[2][4], ql[2][4];
#pragma unroll
    for (int bt = 0; bt < 2; bt++)
#pragma unroll
        for (int kk = 0; kk < 4; kk++) {
            const int o = (brow + bt * 16 + lr) * H + kk * 32 + g * 8;
            qh[bt][kk] = ldb(qt_hi + o);
            ql[bt][kk] = ldb(qt_lo + o);
        }
    f32x4 acc[2][8];
#pragma unroll
    for (int bt = 0; bt < 2; bt++)
#pragma unroll
        for (int dt = 0; dt < 8; dt++) acc[bt][dt] = (f32x4){0.f, 0.f, 0.f, 0.f};
    float mb0 = 0.f, sm0 = 0.f, mb1 = 0.f, sm1 = 0.f;
    us* Ph = lds + w * 2304;
    us* Pl = Ph + 1152;
    for (int m0 = m0b; m0 < m0b + mchunk; m0 += 32) {
        f32x4 c[2][2];  // [mt][bt]
#pragma unroll
        for (int mt = 0; mt < 2; mt++)
#pragma unroll
            for (int bt = 0; bt < 2; bt++) c[mt][bt] = (f32x4){0.f, 0.f, 0.f, 0.f};
#pragma unroll
        for (int kk = 0; kk < 4; kk++) {
            const int o0 = (m0 + lr) * H + kk * 32 + g * 8;
            const int o1 = o0 + 16 * H;
            bf8 a0h = ldb(memw_hi + o0), a0l = ldb(memw_lo + o0);
            bf8 a1h = ldb(memw_hi + o1), a1l = ldb(memw_lo + o1);
            c[0][0] = MFMA(a0h, qh[0][kk], c[0][0], 0, 0, 0);
            c[0][0] = MFMA(a0l, qh[0][kk], c[0][0], 0, 0, 0);
            c[0][0] = MFMA(a0h, ql[0][kk], c[0][0], 0, 0, 0);
            c[0][1] = MFMA(a0h, qh[1][kk], c[0][1], 0, 0, 0);
            c[0][1] = MFMA(a0l, qh[1][kk], c[0][1], 0, 0, 0);
            c[0][1] = MFMA(a0h, ql[1][kk], c[0][1], 0, 0, 0);
            c[1][0] = MFMA(a1h, qh[0][kk], c[1][0], 0, 0, 0);
            c[1][0] = MFMA(a1l, qh[0][kk], c[1][0], 0, 0, 0);
            c[1][0] = MFMA(a1h, ql[0][kk], c[1][0], 0, 0, 0);
            c[1][1] = MFMA(a1h, qh[1][kk], c[1][1], 0, 0, 0);
            c[1][1] = MFMA(a1l, qh[1][kk], c[1][1], 0, 0, 0);
            c[1][1] = MFMA(a1h, ql[1][kk], c[1][1], 0, 0, 0);
        }
        float s[2][2][4];
        float lmax0 = -INFINITY, lmax1 = -INFINITY;
#pragma unroll
        for (int mt = 0; mt < 2; mt++)
#pragma unroll
            for (int r = 0; r < 4; r++) {
                s[mt][0][r] = c[mt][0][r] * SCALE2;
                s[mt][1][r] = c[mt][1][r] * SCALE2;
                lmax0 = fmaxf(lmax0, s[mt][0][r]);
                lmax1 = fmaxf(lmax1, s[mt][1][r]);
            }
        lmax0 = fmaxf(lmax0, __shfl_xor(lmax0, 16));
        lmax0 = fmaxf(lmax0, __shfl_xor(lmax0, 32));
        lmax1 = fmaxf(lmax1, __shfl_xor(lmax1, 16));
        lmax1 = fmaxf(lmax1, __shfl_xor(lmax1, 32));
        if (__any((lmax0 > mb0 + 8.f) || (lmax1 > mb1 + 8.f))) {
            float nm0 = fmaxf(mb0, lmax0), f0 = __expf(mb0 - nm0);
            float nm1 = fmaxf(mb1, lmax1), f1 = __expf(mb1 - nm1);
            sm0 *= f0; sm1 *= f1;
            float fr0[4], fr1[4];
#pragma unroll
            for (int r = 0; r < 4; r++) {
                fr0[r] = __shfl(f0, g * 4 + r);
                fr1[r] = __shfl(f1, g * 4 + r);
            }
#pragma unroll
            for (int dt = 0; dt < 8; dt++)
#pragma unroll
                for (int r = 0; r < 4; r++) {
                    acc[0][dt][r] *= fr0[r];
                    acc[1][dt][r] *= fr1[r];
                }
            mb0 = nm0; mb1 = nm1;
        }
#pragma unroll
        for (int bt = 0; bt < 2; bt++) {
            const float mbx = bt ? mb1 : mb0;
#pragma unroll
            for (int mt = 0; mt < 2; mt++) {
                us hh[4], ll[4];
#pragma unroll
                for (int r = 0; r < 4; r++) {
                    float p = __expf(s[mt][bt][r] - mbx);
                    if (bt) sm1 += p; else sm0 += p;
                    split2(p, &hh[r], &ll[r]);
                }
                uint2 v;
                v.x = (unsigned)hh[0] | ((unsigned)hh[1] << 16);
                v.y = (unsigned)hh[2] | ((unsigned)hh[3] << 16);
                *(uint2*)(Ph + (bt * 16 + lr) * PST + mt * 16 + g * 4) = v;
                v.x = (unsigned)ll[0] | ((unsigned)ll[1] << 16);
                v.y = (unsigned)ll[2] | ((unsigned)ll[3] << 16);
                *(uint2*)(Pl + (bt * 16 + lr) * PST + mt * 16 + g * 4) = v;
            }
        }
        bf8 pah[2], pal[2];
#pragma unroll
        for (int bt = 0; bt < 2; bt++) {
            pah[bt] = *(const bf8*)(Ph + (bt * 16 + lr) * PST + g * 8);
            pal[bt] = *(const bf8*)(Pl + (bt * 16 + lr) * PST + g * 8);
        }
#pragma unroll
        for (int dt = 0; dt < 8; dt++) {
            const int to = (dt * 16 + lr) * M + m0 + g * 8;
            bf8 th = ldb(memwT_hi + to), tl = ldb(memwT_lo + to);
            acc[0][dt] = MFMA(pah[0], th, acc[0][dt], 0, 0, 0);
            acc[0][dt] = MFMA(pal[0], th, acc[0][dt], 0, 0, 0);
            acc[0][dt] = MFMA(pah[0], tl, acc[0][dt], 0, 0, 0);
            acc[1][dt] = MFMA(pah[1], th, acc[1][dt], 0, 0, 0);
            acc[1][dt] = MFMA(pal[1], th, acc[1][dt], 0, 0, 0);
            acc[1][dt] = MFMA(pah[1], tl, acc[1][dt], 0, 0, 0);
        }
    }
    sm0 += __shfl_xor(sm0, 16); sm0 += __shfl_xor(sm0, 32);
    sm1 += __shfl_xor(sm1, 16); sm1 += __shfl_xor(sm1, 32);
    if (g == 0) {
        pmax2[(size_t)blockIdx.y * B + brow + lr] = mb0;
        psum2[(size_t)blockIdx.y * B + brow + lr] = sm0;
        pmax2[(size_t)blockIdx.y * B + brow + 16 + lr] = mb1;
        psum2[(size_t)blockIdx.y * B + brow + 16 + lr] = sm1;
    }
    float* rp = part + (size_t)blockIdx.y * B * H;
#pragma unroll
    for (int bt = 0; bt < 2; bt++)
#pragma unroll
        for (int dt = 0; dt < 8; dt++)
#pragma unroll
            for (int r = 0; r < 4; r++)
                rp[(size_t)(brow + bt * 16 + g * 4 + r) * H + dt * 16 + lr] =
                    acc[bt][dt][r];
}

// ---------------- K8: per-b chunk weights ------------------------------------
__global__ __launch_bounds__(256) void k_fstats(const float* __restrict__ pmax2,
        const float* __restrict__ psum2, float* __restrict__ wc, int nc) {
    const int b = blockIdx.x * 256 + threadIdx.x;
    float gm = -INFINITY;
    for (int c = 0; c < nc; c++) gm = fmaxf(gm, pmax2[(size_t)c * B + b]);
    float z = 0.f;
    for (int c = 0; c < nc; c++)
        z += psum2[(size_t)c * B + b] * __expf(pmax2[(size_t)c * B + b] - gm);
    const float zi = 1.f / z;
    for (int c = 0; c < nc; c++)
        wc[(size_t)c * B + b] = __expf(pmax2[(size_t)c * B + b] - gm) * zi;
}

// ---------------- K9: weighted combine -> out --------------------------------
__global__ __launch_bounds__(256) void k_fcombine(const float* __restrict__ part,
        const float* __restrict__ wc, float* __restrict__ out, int nc) {
    const int i = blockIdx.x * 256 + threadIdx.x;
    const int b = i >> 7;
    float s = 0.f;
    for (int c = 0; c < nc; c++) s += part[(size_t)c * B * H + i] * wc[(size_t)c * B + b];
    out[i] = s;
}

extern "C" void kernel_launch(void* const* d_in, const int* in_sizes, int n_in,
                              void* d_out, int out_size, void* d_ws, size_t ws_size,
                              hipStream_t stream) {
    const float* ts     = (const float*)d_in[0];
    const float* inp    = (const float*)d_in[1];
    const float* memory = (const float*)d_in[2];
    const float* w_t    = (const float*)d_in[3];
    const float* b_t    = (const float*)d_in[4];
    const float* Wq     = (const float*)d_in[5];
    const float* Wk     = (const float*)d_in[6];
    const float* Wv     = (const float*)d_in[7];
    float* out = (float*)d_out;

    char* p = (char*)d_ws;
    auto alloc = [&](size_t bytes) { char* r = p; p += (bytes + 255) & ~(size_t)255; return r; };
    us* mem_hi   = (us*)alloc((size_t)M * H * 2);
    us* mem_lo   = (us*)alloc((size_t)M * H * 2);
    us* memw_hi  = (us*)alloc((size_t)M * H * 2);
    us* memw_lo  = (us*)alloc((size_t)M * H * 2);
    us* memwT_hi = (us*)alloc((size_t)M * H * 2);
    us* memwT_lo = (us*)alloc((size_t)M * H * 2);
    us* qt_hi    = (us*)alloc((size_t)B * H * 2);
    us* qt_lo    = (us*)alloc((size_t)B * H * 2);
    us* vhT_hi   = (us*)alloc((size_t)B * H * 2);
    us* vhT_lo   = (us*)alloc((size_t)B * H * 2);
    float* vh    = (float*)alloc((size_t)B * H * 4);
    float* pmax  = (float*)alloc((size_t)B * SC * 4);
    float* psum  = (float*)alloc((size_t)B * SC * 4);
    float* ffac  = (float*)alloc((size_t)B * 4);
    size_t remain = ws_size - (size_t)(p - (char*)d_ws);
    int NC = 1;
    for (int c = 64; c >= 1; c >>= 1) {
        size_t need = (size_t)c * B * H * 4 + 3 * (size_t)c * B * 4 + 4096;
        if (need <= remain) { NC = c; break; }
    }
    float* pmax2 = (float*)alloc((size_t)NC * B * 4);
    float* psum2 = (float*)alloc((size_t)NC * B * 4);
    float* wcb   = (float*)alloc((size_t)NC * B * 4);
    float* part  = (float*)alloc((size_t)NC * B * H * 4);
    const int mchunk = M / NC;

    hipLaunchKernelGGL(k_prep, dim3(B), dim3(128), 0, stream,
                       ts, inp, w_t, b_t, Wq, Wk, Wv, qt_hi, qt_lo, vh);
    hipLaunchKernelGGL(k_splitmem, dim3(2048), dim3(256), 0, stream,
                       memory, mem_hi, mem_lo, M * H);
    hipLaunchKernelGGL(k_tx, dim3(H, B / 256), dim3(256), 0, stream, vh, vhT_hi, vhT_lo);
    hipLaunchKernelGGL(k_stats, dim3(B / 128, SC), dim3(256), 0, stream,
                       mem_hi, mem_lo, qt_hi, qt_lo, M / SC, pmax, psum);
    hipLaunchKernelGGL(k_combine1, dim3(B / 256), dim3(256), 0, stream, pmax, psum, ffac);
    hipLaunchKernelGGL(k_update, dim3(M / 128), dim3(256), 0, stream,
                       memory, mem_hi, mem_lo, qt_hi, qt_lo, vhT_hi, vhT_lo,
                       ffac, memw_hi, memw_lo, memwT_hi, memwT_lo);
    hipLaunchKernelGGL(k_fread, dim3(B / 128, NC), dim3(256), 0, stream,
                       memw_hi, memw_lo, memwT_hi, memwT_lo, qt_hi, qt_lo,
                       part, pmax2, psum2, mchunk);
    hipLaunchKernelGGL(k_fstats, dim3(B / 256), dim3(256), 0, stream, pmax2, psum2, wcb, NC);
    hipLaunchKernelGGL(k_fcombine, dim3(B * H / 256), dim3(256), 0, stream, part, wcb, out, NC);
}

// Round 7
// 783.908 us; speedup vs baseline: 12.1509x; 1.9505x over previous
//
#include <hip/hip_runtime.h>
#include <math.h>

#define B 2048
#define M 65536
#define H 128
#define TDIM 128
#define IDIM 256
#define SC 32            // stats-1 chunks over M
#define SCALE2 0.08838834764831845f
#define PST 36           // padded P-tile row stride (us units)

typedef short bf8 __attribute__((ext_vector_type(8)));
typedef float f32x4 __attribute__((ext_vector_type(4)));
#define MFMA __builtin_amdgcn_mfma_f32_16x16x32_bf16
typedef unsigned short us;

__device__ inline us f2bf(float x) {
    unsigned u = __float_as_uint(x);
    u += 0x7FFF + ((u >> 16) & 1);
    return (us)(u >> 16);
}
__device__ inline float bf2f(us h) { return __uint_as_float(((unsigned)h) << 16); }
__device__ inline void split2(float x, us* hi, us* lo) {
    us h = f2bf(x); *hi = h; *lo = f2bf(x - bf2f(h));
}
__device__ inline bf8 ldb(const us* p) { return *(const bf8*)p; }
__device__ inline void gload16(const void* g, void* l) {
    __builtin_amdgcn_global_load_lds(
        (const __attribute__((address_space(1))) unsigned int*)g,
        (__attribute__((address_space(3))) unsigned int*)l, 16, 0, 0);
}

// ---------------- K1: prep: qt = ((cos-enc)@Wq^T)@Wk -> bf16 hi/lo; vh fp32 --
__global__ __launch_bounds__(128) void k_prep(const float* __restrict__ ts,
        const float* __restrict__ inp, const float* __restrict__ w_t,
        const float* __restrict__ b_t, const float* __restrict__ Wq,
        const float* __restrict__ Wk, const float* __restrict__ Wv,
        us* __restrict__ qt_hi, us* __restrict__ qt_lo, float* __restrict__ vh) {
    __shared__ float temb[TDIM];
    __shared__ float qh[H];
    const int b = blockIdx.x, t = threadIdx.x;
    temb[t] = cosf(ts[b] * w_t[t] + b_t[t]);
    __syncthreads();
    float s = 0.f;
    for (int k = 0; k < TDIM; k++) s += temb[k] * Wq[t * TDIM + k];
    qh[t] = s;
    __syncthreads();
    float s2 = 0.f;
    for (int j = 0; j < H; j++) s2 += qh[j] * Wk[j * H + t];
    us h, l;
    split2(s2, &h, &l);
    qt_hi[b * H + t] = h; qt_lo[b * H + t] = l;
    float s3 = 0.f;
    for (int i = 0; i < IDIM; i++) s3 += inp[b * IDIM + i] * Wv[t * IDIM + i];
    vh[b * H + t] = s3;
}

// ---------------- K2: split memory -> bf16 hi/lo -----------------------------
__global__ __launch_bounds__(256) void k_splitmem(const float* __restrict__ x,
        us* __restrict__ hi, us* __restrict__ lo, int n) {
    int i = blockIdx.x * 256 + threadIdx.x;
    const int stride = gridDim.x * 256;
    for (; i < n; i += stride) {
        us h, l;
        split2(x[i], &h, &l);
        hi[i] = h; lo[i] = l;
    }
}

// ---------------- K3: vh [B][H] -> vhT_hi [H][B] (hi only) -------------------
__global__ __launch_bounds__(256) void k_tx(const float* __restrict__ vh,
        us* __restrict__ vhT_hi) {
    const int d = blockIdx.x;
    const int b = blockIdx.y * 256 + threadIdx.x;
    vhT_hi[d * B + b] = f2bf(vh[b * H + d]);
}

// ---------------- K4: stats pass 1 (deferred-max sumexp over m) --------------
// A=qt (resident, 32 b/wave), B=mem (streamed via LDS staging, 32 m/iter).
__global__ __launch_bounds__(256) void k_stats(const us* __restrict__ src_hi,
        const us* __restrict__ src_lo,
        const us* __restrict__ qt_hi, const us* __restrict__ qt_lo,
        int mchunk, float* __restrict__ pmax, float* __restrict__ psum) {
    __shared__ us lds[16384];  // 2 bufs x (hi 4096 + lo 4096), [32][128] swizzled
    const int tid = threadIdx.x;
    const int w = tid >> 6, l = tid & 63;
    const int lr = l & 15, g = l >> 4;
    const int brow = blockIdx.x * 128 + w * 32;
    const int m0b = blockIdx.y * mchunk;
    const int rq = l >> 4, cq = l & 15;
    bf8 qh[2][4], ql[2][4];
#pragma unroll
    for (int bt = 0; bt < 2; bt++)
#pragma unroll
        for (int kk = 0; kk < 4; kk++) {
            const int o = (brow + bt * 16 + lr) * H + kk * 32 + g * 8;
            qh[bt][kk] = ldb(qt_hi + o);
            ql[bt][kk] = ldb(qt_lo + o);
        }
    float mb[8], sm[8];
#pragma unroll
    for (int i = 0; i < 8; i++) { mb[i] = -INFINITY; sm[i] = 0.f; }
    auto STAGE = [&](int t, int bi) {
        const int m0 = m0b + t * 32;
        us* Q = lds + bi * 8192;
#pragma unroll
        for (int i = 0; i < 4; i++) {
            const int id = w * 4 + i;
            const int ii = id & 7;
            const int r = ii * 4 + rq;
            const int cc = cq ^ (r & 7);
            gload16((id < 8 ? src_hi : src_lo) + (size_t)(m0 + r) * H + cc * 8,
                    Q + (id < 8 ? 0 : 4096) + ii * 512);
        }
    };
    STAGE(0, 0);
    __syncthreads();
    int cur = 0;
    const int NT = mchunk / 32;
    for (int t = 0; t < NT; t++) {
        if (t + 1 < NT) STAGE(t + 1, cur ^ 1);
        const us* Q = lds + cur * 8192;
        f32x4 c[2][2];  // [bt][mt]
#pragma unroll
        for (int bt = 0; bt < 2; bt++)
#pragma unroll
            for (int mt = 0; mt < 2; mt++) c[bt][mt] = (f32x4){0.f, 0.f, 0.f, 0.f};
#pragma unroll
        for (int kk = 0; kk < 4; kk++) {
            const int co = ((kk * 4 + g) ^ (lr & 7)) * 8;
            bf8 b0h = *(const bf8*)(Q + lr * 128 + co);
            bf8 b0l = *(const bf8*)(Q + 4096 + lr * 128 + co);
            bf8 b1h = *(const bf8*)(Q + (16 + lr) * 128 + co);
            bf8 b1l = *(const bf8*)(Q + 4096 + (16 + lr) * 128 + co);
            c[0][0] = MFMA(qh[0][kk], b0h, c[0][0], 0, 0, 0);
            c[0][0] = MFMA(ql[0][kk], b0h, c[0][0], 0, 0, 0);
            c[0][0] = MFMA(qh[0][kk], b0l, c[0][0], 0, 0, 0);
            c[0][1] = MFMA(qh[0][kk], b1h, c[0][1], 0, 0, 0);
            c[0][1] = MFMA(ql[0][kk], b1h, c[0][1], 0, 0, 0);
            c[0][1] = MFMA(qh[0][kk], b1l, c[0][1], 0, 0, 0);
            c[1][0] = MFMA(qh[1][kk], b0h, c[1][0], 0, 0, 0);
            c[1][0] = MFMA(ql[1][kk], b0h, c[1][0], 0, 0, 0);
            c[1][0] = MFMA(qh[1][kk], b0l, c[1][0], 0, 0, 0);
            c[1][1] = MFMA(qh[1][kk], b1h, c[1][1], 0, 0, 0);
            c[1][1] = MFMA(ql[1][kk], b1h, c[1][1], 0, 0, 0);
            c[1][1] = MFMA(qh[1][kk], b1l, c[1][1], 0, 0, 0);
        }
        float dm = -INFINITY;
#pragma unroll
        for (int bt = 0; bt < 2; bt++)
#pragma unroll
            for (int mt = 0; mt < 2; mt++)
#pragma unroll
                for (int r = 0; r < 4; r++)
                    dm = fmaxf(dm, c[bt][mt][r] - mb[bt * 4 + r]);
        if (__any(dm > 8.f)) {
#pragma unroll
            for (int bt = 0; bt < 2; bt++)
#pragma unroll
                for (int r = 0; r < 4; r++) {
                    const int s = bt * 4 + r;
                    float mx = fmaxf(mb[s], fmaxf(c[bt][0][r], c[bt][1][r]));
                    sm[s] = sm[s] * __expf(mb[s] - mx)
                          + __expf(c[bt][0][r] - mx) + __expf(c[bt][1][r] - mx);
                    mb[s] = mx;
                }
        } else {
#pragma unroll
            for (int bt = 0; bt < 2; bt++)
#pragma unroll
                for (int r = 0; r < 4; r++) {
                    const int s = bt * 4 + r;
                    sm[s] += __expf(c[bt][0][r] - mb[s]) + __expf(c[bt][1][r] - mb[s]);
                }
        }
        __syncthreads();
        cur ^= 1;
    }
#pragma unroll
    for (int s = 0; s < 8; s++) {
#pragma unroll
        for (int x = 1; x < 16; x <<= 1) {
            float om = __shfl_xor(mb[s], x);
            float os = __shfl_xor(sm[s], x);
            float nm = fmaxf(mb[s], om);
            sm[s] = sm[s] * __expf(mb[s] - nm) + os * __expf(om - nm);
            mb[s] = nm;
        }
    }
    if (lr == 0) {
#pragma unroll
        for (int bt = 0; bt < 2; bt++)
#pragma unroll
            for (int r = 0; r < 4; r++) {
                const int row = brow + bt * 16 + g * 4 + r;
                pmax[row * SC + blockIdx.y] = mb[bt * 4 + r];
                psum[row * SC + blockIdx.y] = sm[bt * 4 + r];
            }
    }
}

// ---------------- K5: combine -> ffac[b] = exp(-gmax)/Z ----------------------
__global__ __launch_bounds__(256) void k_combine1(const float* __restrict__ pmax,
        const float* __restrict__ psum, float* __restrict__ ffac) {
    const int b = blockIdx.x * 256 + threadIdx.x;
    float mx = -INFINITY;
    for (int c = 0; c < SC; c++) mx = fmaxf(mx, pmax[b * SC + c]);
    float z = 0.f;
    for (int c = 0; c < SC; c++) z += psum[b * SC + c] * __expf(pmax[b * SC + c] - mx);
    ffac[b] = __expf(-mx) / z;
}

// ---------------- K6: update: memw = normalize(memory + P1^T @ vh) -----------
// qt staged double-buffered; vhT_hi staged single-buffered (post-barrier).
// PV = (P_hi + P_lo) * V_hi (V-lo term dropped).
__global__ __launch_bounds__(256) void k_update(const float* __restrict__ memory,
        const us* __restrict__ mem_hi, const us* __restrict__ mem_lo,
        const us* __restrict__ qt_hi, const us* __restrict__ qt_lo,
        const us* __restrict__ vhT_hi, const float* __restrict__ ffac,
        us* __restrict__ memw_hi, us* __restrict__ memw_lo,
        us* __restrict__ memwT_hi) {
    __shared__ us lds[29696]; // qt dbuf 2x8192 | vhT 4096 | P 4x2304; epi reuses [0,17408)
    const int tid = threadIdx.x;
    const int w = tid >> 6, l = tid & 63;
    const int lr = l & 15, g = l >> 4;
    const int mrow = blockIdx.x * 128 + w * 32;
    const int rq = l >> 4, cq = l & 15;
    const int rv = l >> 2, cv = l & 3;
    bf8 bh[2][4], bl[2][4];
#pragma unroll
    for (int t = 0; t < 2; t++)
#pragma unroll
        for (int kk = 0; kk < 4; kk++) {
            const int o = (mrow + t * 16 + lr) * H + kk * 32 + g * 8;
            bh[t][kk] = ldb(mem_hi + o);
            bl[t][kk] = ldb(mem_lo + o);
        }
    f32x4 acc[2][8];
#pragma unroll
    for (int t = 0; t < 2; t++)
#pragma unroll
        for (int dt = 0; dt < 8; dt++) acc[t][dt] = (f32x4){0.f, 0.f, 0.f, 0.f};
    us* Ph = lds + 20480 + w * 2304;
    us* Pl = Ph + 1152;
    auto STAGE_QT = [&](int t, int bi) {
        const int b0 = t * 32;
        us* Q = lds + bi * 8192;
#pragma unroll
        for (int i = 0; i < 4; i++) {
            const int id = w * 4 + i;
            const int ii = id & 7;
            const int r = ii * 4 + rq;
            const int cc = cq ^ (r & 7);
            gload16((id < 8 ? qt_hi : qt_lo) + (size_t)(b0 + r) * H + cc * 8,
                    Q + (id < 8 ? 0 : 4096) + ii * 512);
        }
    };
    auto STAGE_VH = [&](int t) {
        const int b0 = t * 32;
        us* V = lds + 16384;
#pragma unroll
        for (int i = 0; i < 2; i++) {
            const int j = w * 2 + i;
            const int r = j * 16 + rv;
            const int cc = cv ^ ((rv >> 1) & 3);
            gload16(vhT_hi + (size_t)r * B + b0 + cc * 8, V + j * 512);
        }
    };
    STAGE_QT(0, 0);
    STAGE_VH(0);
    __syncthreads();
    int cur = 0;
    const int NT = B / 32;
    const us* V = lds + 16384;
    for (int t = 0; t < NT; t++) {
        if (t + 1 < NT) STAGE_QT(t + 1, cur ^ 1);
        const us* Q = lds + cur * 8192;
        f32x4 c[2][2];  // [bt][mt]
#pragma unroll
        for (int bt = 0; bt < 2; bt++)
#pragma unroll
            for (int mt = 0; mt < 2; mt++) c[bt][mt] = (f32x4){0.f, 0.f, 0.f, 0.f};
#pragma unroll
        for (int kk = 0; kk < 4; kk++) {
            const int co = ((kk * 4 + g) ^ (lr & 7)) * 8;
            bf8 a0h = *(const bf8*)(Q + lr * 128 + co);
            bf8 a0l = *(const bf8*)(Q + 4096 + lr * 128 + co);
            bf8 a1h = *(const bf8*)(Q + (16 + lr) * 128 + co);
            bf8 a1l = *(const bf8*)(Q + 4096 + (16 + lr) * 128 + co);
            c[0][0] = MFMA(a0h, bh[0][kk], c[0][0], 0, 0, 0);
            c[0][0] = MFMA(a0l, bh[0][kk], c[0][0], 0, 0, 0);
            c[0][0] = MFMA(a0h, bl[0][kk], c[0][0], 0, 0, 0);
            c[0][1] = MFMA(a0h, bh[1][kk], c[0][1], 0, 0, 0);
            c[0][1] = MFMA(a0l, bh[1][kk], c[0][1], 0, 0, 0);
            c[0][1] = MFMA(a0h, bl[1][kk], c[0][1], 0, 0, 0);
            c[1][0] = MFMA(a1h, bh[0][kk], c[1][0], 0, 0, 0);
            c[1][0] = MFMA(a1l, bh[0][kk], c[1][0], 0, 0, 0);
            c[1][0] = MFMA(a1h, bl[0][kk], c[1][0], 0, 0, 0);
            c[1][1] = MFMA(a1h, bh[1][kk], c[1][1], 0, 0, 0);
            c[1][1] = MFMA(a1l, bh[1][kk], c[1][1], 0, 0, 0);
            c[1][1] = MFMA(a1h, bl[1][kk], c[1][1], 0, 0, 0);
        }
        const int b0 = t * 32;
        const float4 f4a = *(const float4*)(ffac + b0 + g * 4);
        const float4 f4b = *(const float4*)(ffac + b0 + 16 + g * 4);
        float fa[4] = {f4a.x, f4a.y, f4a.z, f4a.w};
        float fb[4] = {f4b.x, f4b.y, f4b.z, f4b.w};
#pragma unroll
        for (int bt = 0; bt < 2; bt++) {
#pragma unroll
            for (int mt = 0; mt < 2; mt++) {
                us hh[4], ll[4];
#pragma unroll
                for (int r = 0; r < 4; r++) {
                    float p = __expf(c[bt][mt][r]) * (bt ? fb[r] : fa[r]);
                    split2(p, &hh[r], &ll[r]);
                }
                uint2 v;
                v.x = (unsigned)hh[0] | ((unsigned)hh[1] << 16);
                v.y = (unsigned)hh[2] | ((unsigned)hh[3] << 16);
                *(uint2*)(Ph + (mt * 16 + lr) * PST + bt * 16 + g * 4) = v;
                v.x = (unsigned)ll[0] | ((unsigned)ll[1] << 16);
                v.y = (unsigned)ll[2] | ((unsigned)ll[3] << 16);
                *(uint2*)(Pl + (mt * 16 + lr) * PST + bt * 16 + g * 4) = v;
            }
        }
        bf8 pah[2], pal[2];
#pragma unroll
        for (int mt = 0; mt < 2; mt++) {
            pah[mt] = *(const bf8*)(Ph + (mt * 16 + lr) * PST + g * 8);
            pal[mt] = *(const bf8*)(Pl + (mt * 16 + lr) * PST + g * 8);
        }
        __syncthreads();   // B: V(t) staged-loads drained & visible
#pragma unroll
        for (int dt = 0; dt < 8; dt++) {
            bf8 vhh = *(const bf8*)(V + (dt * 16 + lr) * 32
                                      + ((g ^ ((lr >> 1) & 3)) * 8));
            acc[0][dt] = MFMA(pah[0], vhh, acc[0][dt], 0, 0, 0);
            acc[0][dt] = MFMA(pal[0], vhh, acc[0][dt], 0, 0, 0);
            acc[1][dt] = MFMA(pah[1], vhh, acc[1][dt], 0, 0, 0);
            acc[1][dt] = MFMA(pal[1], vhh, acc[1][dt], 0, 0, 0);
        }
        __syncthreads();   // A: all PV reads of V done
        if (t + 1 < NT) STAGE_VH(t + 1);
        cur ^= 1;
    }
    // epilogue: new = memory + acc; L2-normalize; write memw_hi/lo + memwT_hi
    float n2[2][4];
#pragma unroll
    for (int t = 0; t < 2; t++)
#pragma unroll
        for (int r = 0; r < 4; r++) n2[t][r] = 0.f;
#pragma unroll
    for (int t = 0; t < 2; t++)
#pragma unroll
        for (int dt = 0; dt < 8; dt++)
#pragma unroll
            for (int r = 0; r < 4; r++) {
                float v = acc[t][dt][r]
                        + memory[(mrow + t * 16 + g * 4 + r) * H + dt * 16 + lr];
                acc[t][dt][r] = v;
                n2[t][r] += v * v;
            }
#pragma unroll
    for (int t = 0; t < 2; t++)
#pragma unroll
        for (int r = 0; r < 4; r++) {
#pragma unroll
            for (int x = 1; x < 16; x <<= 1) n2[t][r] += __shfl_xor(n2[t][r], x);
            n2[t][r] = 1.f / fmaxf(sqrtf(n2[t][r]), 1e-12f);
        }
#pragma unroll
    for (int t = 0; t < 2; t++)
#pragma unroll
        for (int dt = 0; dt < 8; dt++)
#pragma unroll
            for (int r = 0; r < 4; r++) {
                float vv = acc[t][dt][r] * n2[t][r];
                us h = f2bf(vv);
                memw_hi[(mrow + t * 16 + g * 4 + r) * H + dt * 16 + lr] = h;
                memw_lo[(mrow + t * 16 + g * 4 + r) * H + dt * 16 + lr]
                    = f2bf(vv - bf2f(h));
                lds[(dt * 16 + lr) * 136 + w * 32 + t * 16 + g * 4 + r] = h;
            }
    __syncthreads();
    {
        const int d = tid >> 1, seg = tid & 1;
        uint4* dq = (uint4*)(memwT_hi + (size_t)d * M + blockIdx.x * 128 + seg * 64);
        const uint4* sp = (const uint4*)(lds + d * 136 + seg * 64);
#pragma unroll
        for (int j = 0; j < 8; j++) dq[j] = sp[j];
    }
}

// ---------------- K7: flash read: fused stats2 + PV over m-chunks ------------
// memw staged double-buffered; memwT_hi staged single-buffered.
// PV = (P_hi + P_lo) * memwT_hi (lo term dropped).
__global__ __launch_bounds__(256) void k_fread(const us* __restrict__ memw_hi,
        const us* __restrict__ memw_lo, const us* __restrict__ memwT_hi,
        const us* __restrict__ qt_hi, const us* __restrict__ qt_lo,
        float* __restrict__ part, float* __restrict__ pmax2,
        float* __restrict__ psum2, int mchunk) {
    __shared__ us lds[29696];
    const int tid = threadIdx.x;
    const int w = tid >> 6, l = tid & 63;
    const int lr = l & 15, g = l >> 4;
    const int brow = blockIdx.x * 128 + w * 32;
    const int m0b = blockIdx.y * mchunk;
    const int rq = l >> 4, cq = l & 15;
    const int rv = l >> 2, cv = l & 3;
    bf8 qh[2][4], ql[2][4];
#pragma unroll
    for (int bt = 0; bt < 2; bt++)
#pragma unroll
        for (int kk = 0; kk < 4; kk++) {
            const int o = (brow + bt * 16 + lr) * H + kk * 32 + g * 8;
            qh[bt][kk] = ldb(qt_hi + o);
            ql[bt][kk] = ldb(qt_lo + o);
        }
    f32x4 acc[2][8];
#pragma unroll
    for (int bt = 0; bt < 2; bt++)
#pragma unroll
        for (int dt = 0; dt < 8; dt++) acc[bt][dt] = (f32x4){0.f, 0.f, 0.f, 0.f};
    float mb0 = 0.f, sm0 = 0.f, mb1 = 0.f, sm1 = 0.f;
    us* Ph = lds + 20480 + w * 2304;
    us* Pl = Ph + 1152;
    auto STAGE_MW = [&](int t, int bi) {
        const int m0 = m0b + t * 32;
        us* Q = lds + bi * 8192;
#pragma unroll
        for (int i = 0; i < 4; i++) {
            const int id = w * 4 + i;
            const int ii = id & 7;
            const int r = ii * 4 + rq;
            const int cc = cq ^ (r & 7);
            gload16((id < 8 ? memw_hi : memw_lo) + (size_t)(m0 + r) * H + cc * 8,
                    Q + (id < 8 ? 0 : 4096) + ii * 512);
        }
    };
    auto STAGE_WT = [&](int t) {
        const int m0 = m0b + t * 32;
        us* V = lds + 16384;
#pragma unroll
        for (int i = 0; i < 2; i++) {
            const int j = w * 2 + i;
            const int r = j * 16 + rv;
            const int cc = cv ^ ((rv >> 1) & 3);
            gload16(memwT_hi + (size_t)r * M + m0 + cc * 8, V + j * 512);
        }
    };
    STAGE_MW(0, 0);
    STAGE_WT(0);
    __syncthreads();
    int cur = 0;
    const int NT = mchunk / 32;
    const us* V = lds + 16384;
    for (int t = 0; t < NT; t++) {
        if (t + 1 < NT) STAGE_MW(t + 1, cur ^ 1);
        const us* Q = lds + cur * 8192;
        f32x4 c[2][2];  // [mt][bt]
#pragma unroll
        for (int mt = 0; mt < 2; mt++)
#pragma unroll
            for (int bt = 0; bt < 2; bt++) c[mt][bt] = (f32x4){0.f, 0.f, 0.f, 0.f};
#pragma unroll
        for (int kk = 0; kk < 4; kk++) {
            const int co = ((kk * 4 + g) ^ (lr & 7)) * 8;
            bf8 a0h = *(const bf8*)(Q + lr * 128 + co);
            bf8 a0l = *(const bf8*)(Q + 4096 + lr * 128 + co);
            bf8 a1h = *(const bf8*)(Q + (16 + lr) * 128 + co);
            bf8 a1l = *(const bf8*)(Q + 4096 + (16 + lr) * 128 + co);
            c[0][0] = MFMA(a0h, qh[0][kk], c[0][0], 0, 0, 0);
            c[0][0] = MFMA(a0l, qh[0][kk], c[0][0], 0, 0, 0);
            c[0][0] = MFMA(a0h, ql[0][kk], c[0][0], 0, 0, 0);
            c[0][1] = MFMA(a0h, qh[1][kk], c[0][1], 0, 0, 0);
            c[0][1] = MFMA(a0l, qh[1][kk], c[0][1], 0, 0, 0);
            c[0][1] = MFMA(a0h, ql[1][kk], c[0][1], 0, 0, 0);
            c[1][0] = MFMA(a1h, qh[0][kk], c[1][0], 0, 0, 0);
            c[1][0] = MFMA(a1l, qh[0][kk], c[1][0], 0, 0, 0);
            c[1][0] = MFMA(a1h, ql[0][kk], c[1][0], 0, 0, 0);
            c[1][1] = MFMA(a1h, qh[1][kk], c[1][1], 0, 0, 0);
            c[1][1] = MFMA(a1l, qh[1][kk], c[1][1], 0, 0, 0);
            c[1][1] = MFMA(a1h, ql[1][kk], c[1][1], 0, 0, 0);
        }
        float s[2][2][4];
        float lmax0 = -INFINITY, lmax1 = -INFINITY;
#pragma unroll
        for (int mt = 0; mt < 2; mt++)
#pragma unroll
            for (int r = 0; r < 4; r++) {
                s[mt][0][r] = c[mt][0][r] * SCALE2;
                s[mt][1][r] = c[mt][1][r] * SCALE2;
                lmax0 = fmaxf(lmax0, s[mt][0][r]);
                lmax1 = fmaxf(lmax1, s[mt][1][r]);
            }
        lmax0 = fmaxf(lmax0, __shfl_xor(lmax0, 16));
        lmax0 = fmaxf(lmax0, __shfl_xor(lmax0, 32));
        lmax1 = fmaxf(lmax1, __shfl_xor(lmax1, 16));
        lmax1 = fmaxf(lmax1, __shfl_xor(lmax1, 32));
        if (__any((lmax0 > mb0 + 8.f) || (lmax1 > mb1 + 8.f))) {
            float nm0 = fmaxf(mb0, lmax0), f0 = __expf(mb0 - nm0);
            float nm1 = fmaxf(mb1, lmax1), f1 = __expf(mb1 - nm1);
            sm0 *= f0; sm1 *= f1;
            float fr0[4], fr1[4];
#pragma unroll
            for (int r = 0; r < 4; r++) {
                fr0[r] = __shfl(f0, g * 4 + r);
                fr1[r] = __shfl(f1, g * 4 + r);
            }
#pragma unroll
            for (int dt = 0; dt < 8; dt++)
#pragma unroll
                for (int r = 0; r < 4; r++) {
                    acc[0][dt][r] *= fr0[r];
                    acc[1][dt][r] *= fr1[r];
                }
            mb0 = nm0; mb1 = nm1;
        }
#pragma unroll
        for (int bt = 0; bt < 2; bt++) {
            const float mbx = bt ? mb1 : mb0;
#pragma unroll
            for (int mt = 0; mt < 2; mt++) {
                us hh[4], ll[4];
#pragma unroll
                for (int r = 0; r < 4; r++) {
                    float p = __expf(s[mt][bt][r] - mbx);
                    if (bt) sm1 += p; else sm0 += p;
                    split2(p, &hh[r], &ll[r]);
                }
                uint2 v;
                v.x = (unsigned)hh[0] | ((unsigned)hh[1] << 16);
                v.y = (unsigned)hh[2] | ((unsigned)hh[3] << 16);
                *(uint2*)(Ph + (bt * 16 + lr) * PST + mt * 16 + g * 4) = v;
                v.x = (unsigned)ll[0] | ((unsigned)ll[1] << 16);
                v.y = (unsigned)ll[2] | ((unsigned)ll[3] << 16);
                *(uint2*)(Pl + (bt * 16 + lr) * PST + mt * 16 + g * 4) = v;
            }
        }
        bf8 pah[2], pal[2];
#pragma unroll
        for (int bt = 0; bt < 2; bt++) {
            pah[bt] = *(const bf8*)(Ph + (bt * 16 + lr) * PST + g * 8);
            pal[bt] = *(const bf8*)(Pl + (bt * 16 + lr) * PST + g * 8);
        }
        __syncthreads();   // B: memwT(t) ready
#pragma unroll
        for (int dt = 0; dt < 8; dt++) {
            bf8 th = *(const bf8*)(V + (dt * 16 + lr) * 32
                                     + ((g ^ ((lr >> 1) & 3)) * 8));
            acc[0][dt] = MFMA(pah[0], th, acc[0][dt], 0, 0, 0);
            acc[0][dt] = MFMA(pal[0], th, acc[0][dt], 0, 0, 0);
            acc[1][dt] = MFMA(pah[1], th, acc[1][dt], 0, 0, 0);
            acc[1][dt] = MFMA(pal[1], th, acc[1][dt], 0, 0, 0);
        }
        __syncthreads();   // A: PV reads done
        if (t + 1 < NT) STAGE_WT(t + 1);
        cur ^= 1;
    }
    sm0 += __shfl_xor(sm0, 16); sm0 += __shfl_xor(sm0, 32);
    sm1 += __shfl_xor(sm1, 16); sm1 += __shfl_xor(sm1, 32);
    if (g == 0) {
        pmax2[(size_t)blockIdx.y * B + brow + lr] = mb0;
        psum2[(size_t)blockIdx.y * B + brow + lr] = sm0;
        pmax2[(size_t)blockIdx.y * B + brow + 16 + lr] = mb1;
        psum2[(size_t)blockIdx.y * B + brow + 16 + lr] = sm1;
    }
    float* rp = part + (size_t)blockIdx.y * B * H;
#pragma unroll
    for (int bt = 0; bt < 2; bt++)
#pragma unroll
        for (int dt = 0; dt < 8; dt++)
#pragma unroll
            for (int r = 0; r < 4; r++)
                rp[(size_t)(brow + bt * 16 + g * 4 + r) * H + dt * 16 + lr] =
                    acc[bt][dt][r];
}

// ---------------- K8: per-b chunk weights ------------------------------------
__global__ __launch_bounds__(256) void k_fstats(const float* __restrict__ pmax2,
        const float* __restrict__ psum2, float* __restrict__ wc, int nc) {
    const int b = blockIdx.x * 256 + threadIdx.x;
    float gm = -INFINITY;
    for (int c = 0; c < nc; c++) gm = fmaxf(gm, pmax2[(size_t)c * B + b]);
    float z = 0.f;
    for (int c = 0; c < nc; c++)
        z += psum2[(size_t)c * B + b] * __expf(pmax2[(size_t)c * B + b] - gm);
    const float zi = 1.f / z;
    for (int c = 0; c < nc; c++)
        wc[(size_t)c * B + b] = __expf(pmax2[(size_t)c * B + b] - gm) * zi;
}

// ---------------- K9: weighted combine -> out --------------------------------
__global__ __launch_bounds__(256) void k_fcombine(const float* __restrict__ part,
        const float* __restrict__ wc, float* __restrict__ out, int nc) {
    const int i = blockIdx.x * 256 + threadIdx.x;
    const int b = i >> 7;
    float s = 0.f;
    for (int c = 0; c < nc; c++) s += part[(size_t)c * B * H + i] * wc[(size_t)c * B + b];
    out[i] = s;
}

extern "C" void kernel_launch(void* const* d_in, const int* in_sizes, int n_in,
                              void* d_out, int out_size, void* d_ws, size_t ws_size,
                              hipStream_t stream) {
    const float* ts     = (const float*)d_in[0];
    const float* inp    = (const float*)d_in[1];
    const float* memory = (const float*)d_in[2];
    const float* w_t    = (const float*)d_in[3];
    const float* b_t    = (const float*)d_in[4];
    const float* Wq     = (const float*)d_in[5];
    const float* Wk     = (const float*)d_in[6];
    const float* Wv     = (const float*)d_in[7];
    float* out = (float*)d_out;

    char* p = (char*)d_ws;
    auto alloc = [&](size_t bytes) { char* r = p; p += (bytes + 255) & ~(size_t)255; return r; };
    us* mem_hi   = (us*)alloc((size_t)M * H * 2);
    us* mem_lo   = (us*)alloc((size_t)M * H * 2);
    us* memw_hi  = (us*)alloc((size_t)M * H * 2);
    us* memw_lo  = (us*)alloc((size_t)M * H * 2);
    us* memwT_hi = (us*)alloc((size_t)M * H * 2);
    us* qt_hi    = (us*)alloc((size_t)B * H * 2);
    us* qt_lo    = (us*)alloc((size_t)B * H * 2);
    us* vhT_hi   = (us*)alloc((size_t)B * H * 2);
    float* vh    = (float*)alloc((size_t)B * H * 4);
    float* pmax  = (float*)alloc((size_t)B * SC * 4);
    float* psum  = (float*)alloc((size_t)B * SC * 4);
    float* ffac  = (float*)alloc((size_t)B * 4);
    size_t remain = ws_size - (size_t)(p - (char*)d_ws);
    int NC = 1;
    for (int c = 64; c >= 1; c >>= 1) {
        size_t need = (size_t)c * B * H * 4 + 3 * (size_t)c * B * 4 + 4096;
        if (need <= remain) { NC = c; break; }
    }
    float* pmax2 = (float*)alloc((size_t)NC * B * 4);
    float* psum2 = (float*)alloc((size_t)NC * B * 4);
    float* wcb   = (float*)alloc((size_t)NC * B * 4);
    float* part  = (float*)alloc((size_t)NC * B * H * 4);
    const int mchunk = M / NC;

    hipLaunchKernelGGL(k_prep, dim3(B), dim3(128), 0, stream,
                       ts, inp, w_t, b_t, Wq, Wk, Wv, qt_hi, qt_lo, vh);
    hipLaunchKernelGGL(k_splitmem, dim3(2048), dim3(256), 0, stream,
                       memory, mem_hi, mem_lo, M * H);
    hipLaunchKernelGGL(k_tx, dim3(H, B / 256), dim3(256), 0, stream, vh, vhT_hi);
    hipLaunchKernelGGL(k_stats, dim3(B / 128, SC), dim3(256), 0, stream,
                       mem_hi, mem_lo, qt_hi, qt_lo, M / SC, pmax, psum);
    hipLaunchKernelGGL(k_combine1, dim3(B / 256), dim3(256), 0, stream, pmax, psum, ffac);
    hipLaunchKernelGGL(k_update, dim3(M / 128), dim3(256), 0, stream,
                       memory, mem_hi, mem_lo, qt_hi, qt_lo, vhT_hi,
                       ffac, memw_hi, memw_lo, memwT_hi);
    hipLaunchKernelGGL(k_fread, dim3(B / 128, NC), dim3(256), 0, stream,
                       memw_hi, memw_lo, memwT_hi, qt_hi, qt_lo,
                       part, pmax2, psum2, mchunk);
    hipLaunchKernelGGL(k_fstats, dim3(B / 256), dim3(256), 0, stream, pmax2, psum2, wcb, NC);
    hipLaunchKernelGGL(k_fcombine, dim3(B * H / 256), dim3(256), 0, stream, part, wcb, out, NC);
}

// Round 8
// 776.663 us; speedup vs baseline: 12.2643x; 1.0093x over previous
//
#include <hip/hip_runtime.h>
#include <math.h>

#define B 2048
#define M 65536
#define H 128
#define TDIM 128
#define IDIM 256
#define SC 32            // stats-1 chunks over M
#define SCALE2 0.08838834764831845f
#define PST 36           // padded P-tile row stride (us units)

typedef short bf8 __attribute__((ext_vector_type(8)));
typedef float f32x4 __attribute__((ext_vector_type(4)));
#define MFMA __builtin_amdgcn_mfma_f32_16x16x32_bf16
typedef unsigned short us;

// raw barrier + counted vmcnt (T3/T4-lite). sched_barrier pins codegen (rule #18).
#define SBAR() do { __builtin_amdgcn_sched_barrier(0); \
                    __builtin_amdgcn_s_barrier(); \
                    __builtin_amdgcn_sched_barrier(0); } while (0)
#define VMWAIT(N) do { asm volatile("s_waitcnt vmcnt(" #N ")" ::: "memory"); \
                       __builtin_amdgcn_sched_barrier(0); } while (0)

__device__ inline us f2bf(float x) {
    unsigned u = __float_as_uint(x);
    u += 0x7FFF + ((u >> 16) & 1);
    return (us)(u >> 16);
}
__device__ inline float bf2f(us h) { return __uint_as_float(((unsigned)h) << 16); }
__device__ inline void split2(float x, us* hi, us* lo) {
    us h = f2bf(x); *hi = h; *lo = f2bf(x - bf2f(h));
}
__device__ inline bf8 ldb(const us* p) { return *(const bf8*)p; }
__device__ inline void gload16(const void* g, void* l) {
    __builtin_amdgcn_global_load_lds(
        (const __attribute__((address_space(1))) unsigned int*)g,
        (__attribute__((address_space(3))) unsigned int*)l, 16, 0, 0);
}

// ---------------- K1: prep: qt = ((cos-enc)@Wq^T)@Wk -> bf16 hi/lo; vh fp32 --
__global__ __launch_bounds__(128) void k_prep(const float* __restrict__ ts,
        const float* __restrict__ inp, const float* __restrict__ w_t,
        const float* __restrict__ b_t, const float* __restrict__ Wq,
        const float* __restrict__ Wk, const float* __restrict__ Wv,
        us* __restrict__ qt_hi, us* __restrict__ qt_lo, float* __restrict__ vh) {
    __shared__ float temb[TDIM];
    __shared__ float qh[H];
    const int b = blockIdx.x, t = threadIdx.x;
    temb[t] = cosf(ts[b] * w_t[t] + b_t[t]);
    __syncthreads();
    float s = 0.f;
    for (int k = 0; k < TDIM; k++) s += temb[k] * Wq[t * TDIM + k];
    qh[t] = s;
    __syncthreads();
    float s2 = 0.f;
    for (int j = 0; j < H; j++) s2 += qh[j] * Wk[j * H + t];
    us h, l;
    split2(s2, &h, &l);
    qt_hi[b * H + t] = h; qt_lo[b * H + t] = l;
    float s3 = 0.f;
    for (int i = 0; i < IDIM; i++) s3 += inp[b * IDIM + i] * Wv[t * IDIM + i];
    vh[b * H + t] = s3;
}

// ---------------- K2: split memory -> bf16 hi/lo -----------------------------
__global__ __launch_bounds__(256) void k_splitmem(const float* __restrict__ x,
        us* __restrict__ hi, us* __restrict__ lo, int n) {
    int i = blockIdx.x * 256 + threadIdx.x;
    const int stride = gridDim.x * 256;
    for (; i < n; i += stride) {
        us h, l;
        split2(x[i], &h, &l);
        hi[i] = h; lo[i] = l;
    }
}

// ---------------- K3: vh [B][H] -> vhT_hi [H][B] (hi only) -------------------
__global__ __launch_bounds__(256) void k_tx(const float* __restrict__ vh,
        us* __restrict__ vhT_hi) {
    const int d = blockIdx.x;
    const int b = blockIdx.y * 256 + threadIdx.x;
    vhT_hi[d * B + b] = f2bf(vh[b * H + d]);
}

// ---------------- K4: stats pass 1 (deferred-max sumexp over m) --------------
__global__ __launch_bounds__(256) void k_stats(const us* __restrict__ src_hi,
        const us* __restrict__ src_lo,
        const us* __restrict__ qt_hi, const us* __restrict__ qt_lo,
        int mchunk, float* __restrict__ pmax, float* __restrict__ psum) {
    __shared__ us lds[16384];
    const int tid = threadIdx.x;
    const int w = tid >> 6, l = tid & 63;
    const int lr = l & 15, g = l >> 4;
    const int brow = blockIdx.x * 128 + w * 32;
    const int m0b = blockIdx.y * mchunk;
    const int rq = l >> 4, cq = l & 15;
    bf8 qh[2][4], ql[2][4];
#pragma unroll
    for (int bt = 0; bt < 2; bt++)
#pragma unroll
        for (int kk = 0; kk < 4; kk++) {
            const int o = (brow + bt * 16 + lr) * H + kk * 32 + g * 8;
            qh[bt][kk] = ldb(qt_hi + o);
            ql[bt][kk] = ldb(qt_lo + o);
        }
    float mb[8], sm[8];
#pragma unroll
    for (int i = 0; i < 8; i++) { mb[i] = -INFINITY; sm[i] = 0.f; }
    auto STAGE = [&](int t, int bi) {
        const int m0 = m0b + t * 32;
        us* Q = lds + bi * 8192;
#pragma unroll
        for (int i = 0; i < 4; i++) {
            const int id = w * 4 + i;
            const int ii = id & 7;
            const int r = ii * 4 + rq;
            const int cc = cq ^ (r & 7);
            gload16((id < 8 ? src_hi : src_lo) + (size_t)(m0 + r) * H + cc * 8,
                    Q + (id < 8 ? 0 : 4096) + ii * 512);
        }
    };
    STAGE(0, 0);
    int cur = 0;
    const int NT = mchunk / 32;
    for (int t = 0; t < NT; t++) {
        if (t + 1 < NT) { STAGE(t + 1, cur ^ 1); VMWAIT(4); }
        else { VMWAIT(0); }
        SBAR();   // tile t fully landed (all waves)
        const us* Q = lds + cur * 8192;
        f32x4 c[2][2];
#pragma unroll
        for (int bt = 0; bt < 2; bt++)
#pragma unroll
            for (int mt = 0; mt < 2; mt++) c[bt][mt] = (f32x4){0.f, 0.f, 0.f, 0.f};
#pragma unroll
        for (int kk = 0; kk < 4; kk++) {
            const int co = ((kk * 4 + g) ^ (lr & 7)) * 8;
            bf8 b0h = *(const bf8*)(Q + lr * 128 + co);
            bf8 b0l = *(const bf8*)(Q + 4096 + lr * 128 + co);
            bf8 b1h = *(const bf8*)(Q + (16 + lr) * 128 + co);
            bf8 b1l = *(const bf8*)(Q + 4096 + (16 + lr) * 128 + co);
            c[0][0] = MFMA(qh[0][kk], b0h, c[0][0], 0, 0, 0);
            c[0][0] = MFMA(ql[0][kk], b0h, c[0][0], 0, 0, 0);
            c[0][0] = MFMA(qh[0][kk], b0l, c[0][0], 0, 0, 0);
            c[0][1] = MFMA(qh[0][kk], b1h, c[0][1], 0, 0, 0);
            c[0][1] = MFMA(ql[0][kk], b1h, c[0][1], 0, 0, 0);
            c[0][1] = MFMA(qh[0][kk], b1l, c[0][1], 0, 0, 0);
            c[1][0] = MFMA(qh[1][kk], b0h, c[1][0], 0, 0, 0);
            c[1][0] = MFMA(ql[1][kk], b0h, c[1][0], 0, 0, 0);
            c[1][0] = MFMA(qh[1][kk], b0l, c[1][0], 0, 0, 0);
            c[1][1] = MFMA(qh[1][kk], b1h, c[1][1], 0, 0, 0);
            c[1][1] = MFMA(ql[1][kk], b1h, c[1][1], 0, 0, 0);
            c[1][1] = MFMA(qh[1][kk], b1l, c[1][1], 0, 0, 0);
        }
        float dm = -INFINITY;
#pragma unroll
        for (int bt = 0; bt < 2; bt++)
#pragma unroll
            for (int mt = 0; mt < 2; mt++)
#pragma unroll
                for (int r = 0; r < 4; r++)
                    dm = fmaxf(dm, c[bt][mt][r] - mb[bt * 4 + r]);
        if (__any(dm > 8.f)) {
#pragma unroll
            for (int bt = 0; bt < 2; bt++)
#pragma unroll
                for (int r = 0; r < 4; r++) {
                    const int s = bt * 4 + r;
                    float mx = fmaxf(mb[s], fmaxf(c[bt][0][r], c[bt][1][r]));
                    sm[s] = sm[s] * __expf(mb[s] - mx)
                          + __expf(c[bt][0][r] - mx) + __expf(c[bt][1][r] - mx);
                    mb[s] = mx;
                }
        } else {
#pragma unroll
            for (int bt = 0; bt < 2; bt++)
#pragma unroll
                for (int r = 0; r < 4; r++) {
                    const int s = bt * 4 + r;
                    sm[s] += __expf(c[bt][0][r] - mb[s]) + __expf(c[bt][1][r] - mb[s]);
                }
        }
        if (t + 1 < NT) SBAR();   // all reads of buf[cur] done before next overwrite
        cur ^= 1;
    }
#pragma unroll
    for (int s = 0; s < 8; s++) {
#pragma unroll
        for (int x = 1; x < 16; x <<= 1) {
            float om = __shfl_xor(mb[s], x);
            float os = __shfl_xor(sm[s], x);
            float nm = fmaxf(mb[s], om);
            sm[s] = sm[s] * __expf(mb[s] - nm) + os * __expf(om - nm);
            mb[s] = nm;
        }
    }
    if (lr == 0) {
#pragma unroll
        for (int bt = 0; bt < 2; bt++)
#pragma unroll
            for (int r = 0; r < 4; r++) {
                const int row = brow + bt * 16 + g * 4 + r;
                pmax[row * SC + blockIdx.y] = mb[bt * 4 + r];
                psum[row * SC + blockIdx.y] = sm[bt * 4 + r];
            }
    }
}

// ---------------- K5: combine -> ffac[b] = exp(-gmax)/Z ----------------------
__global__ __launch_bounds__(256) void k_combine1(const float* __restrict__ pmax,
        const float* __restrict__ psum, float* __restrict__ ffac) {
    const int b = blockIdx.x * 256 + threadIdx.x;
    float mx = -INFINITY;
    for (int c = 0; c < SC; c++) mx = fmaxf(mx, pmax[b * SC + c]);
    float z = 0.f;
    for (int c = 0; c < SC; c++) z += psum[b * SC + c] * __expf(pmax[b * SC + c] - mx);
    ffac[b] = __expf(-mx) / z;
}

// ---------------- K6: update: memw = normalize(memory + P1^T @ vh) -----------
// Counted-vmcnt schedule: per iter {MW(t+1); vmcnt(6); bar; QK+P; vmcnt(4);
// bar; PV; bar; WT(t+1)} — prefetch never drained at issue.
__global__ __launch_bounds__(256) void k_update(const float* __restrict__ memory,
        const us* __restrict__ mem_hi, const us* __restrict__ mem_lo,
        const us* __restrict__ qt_hi, const us* __restrict__ qt_lo,
        const us* __restrict__ vhT_hi, const float* __restrict__ ffac,
        us* __restrict__ memw_hi, us* __restrict__ memw_lo,
        us* __restrict__ memwT_hi) {
    __shared__ us lds[29696]; // qt dbuf 2x8192 | vhT 4096 | P 4x2304; epi reuses front
    const int tid = threadIdx.x;
    const int w = tid >> 6, l = tid & 63;
    const int lr = l & 15, g = l >> 4;
    const int mrow = blockIdx.x * 128 + w * 32;
    const int rq = l >> 4, cq = l & 15;
    const int rv = l >> 2, cv = l & 3;
    bf8 bh[2][4], bl[2][4];
#pragma unroll
    for (int t = 0; t < 2; t++)
#pragma unroll
        for (int kk = 0; kk < 4; kk++) {
            const int o = (mrow + t * 16 + lr) * H + kk * 32 + g * 8;
            bh[t][kk] = ldb(mem_hi + o);
            bl[t][kk] = ldb(mem_lo + o);
        }
    f32x4 acc[2][8];
#pragma unroll
    for (int t = 0; t < 2; t++)
#pragma unroll
        for (int dt = 0; dt < 8; dt++) acc[t][dt] = (f32x4){0.f, 0.f, 0.f, 0.f};
    us* Ph = lds + 20480 + w * 2304;
    us* Pl = Ph + 1152;
    auto STAGE_QT = [&](int t, int bi) {
        const int b0 = t * 32;
        us* Q = lds + bi * 8192;
#pragma unroll
        for (int i = 0; i < 4; i++) {
            const int id = w * 4 + i;
            const int ii = id & 7;
            const int r = ii * 4 + rq;
            const int cc = cq ^ (r & 7);
            gload16((id < 8 ? qt_hi : qt_lo) + (size_t)(b0 + r) * H + cc * 8,
                    Q + (id < 8 ? 0 : 4096) + ii * 512);
        }
    };
    auto STAGE_VH = [&](int t) {
        const int b0 = t * 32;
        us* V = lds + 16384;
#pragma unroll
        for (int i = 0; i < 2; i++) {
            const int j = w * 2 + i;
            const int r = j * 16 + rv;
            const int cc = cv ^ ((rv >> 1) & 3);
            gload16(vhT_hi + (size_t)r * B + b0 + cc * 8, V + j * 512);
        }
    };
    STAGE_QT(0, 0);
    STAGE_VH(0);
    int cur = 0;
    const int NT = B / 32;
    const us* V = lds + 16384;
    for (int t = 0; t < NT; t++) {
        if (t + 1 < NT) { STAGE_QT(t + 1, cur ^ 1); VMWAIT(6); }
        else { VMWAIT(2); }
        SBAR();   // Q(t) landed for all waves
        const us* Q = lds + cur * 8192;
        f32x4 c[2][2];
#pragma unroll
        for (int bt = 0; bt < 2; bt++)
#pragma unroll
            for (int mt = 0; mt < 2; mt++) c[bt][mt] = (f32x4){0.f, 0.f, 0.f, 0.f};
#pragma unroll
        for (int kk = 0; kk < 4; kk++) {
            const int co = ((kk * 4 + g) ^ (lr & 7)) * 8;
            bf8 a0h = *(const bf8*)(Q + lr * 128 + co);
            bf8 a0l = *(const bf8*)(Q + 4096 + lr * 128 + co);
            bf8 a1h = *(const bf8*)(Q + (16 + lr) * 128 + co);
            bf8 a1l = *(const bf8*)(Q + 4096 + (16 + lr) * 128 + co);
            c[0][0] = MFMA(a0h, bh[0][kk], c[0][0], 0, 0, 0);
            c[0][0] = MFMA(a0l, bh[0][kk], c[0][0], 0, 0, 0);
            c[0][0] = MFMA(a0h, bl[0][kk], c[0][0], 0, 0, 0);
            c[0][1] = MFMA(a0h, bh[1][kk], c[0][1], 0, 0, 0);
            c[0][1] = MFMA(a0l, bh[1][kk], c[0][1], 0, 0, 0);
            c[0][1] = MFMA(a0h, bl[1][kk], c[0][1], 0, 0, 0);
            c[1][0] = MFMA(a1h, bh[0][kk], c[1][0], 0, 0, 0);
            c[1][0] = MFMA(a1l, bh[0][kk], c[1][0], 0, 0, 0);
            c[1][0] = MFMA(a1h, bl[0][kk], c[1][0], 0, 0, 0);
            c[1][1] = MFMA(a1h, bh[1][kk], c[1][1], 0, 0, 0);
            c[1][1] = MFMA(a1l, bh[1][kk], c[1][1], 0, 0, 0);
            c[1][1] = MFMA(a1h, bl[1][kk], c[1][1], 0, 0, 0);
        }
        const int b0 = t * 32;
        const float4 f4a = *(const float4*)(ffac + b0 + g * 4);
        const float4 f4b = *(const float4*)(ffac + b0 + 16 + g * 4);
        float fa[4] = {f4a.x, f4a.y, f4a.z, f4a.w};
        float fb[4] = {f4b.x, f4b.y, f4b.z, f4b.w};
#pragma unroll
        for (int bt = 0; bt < 2; bt++) {
#pragma unroll
            for (int mt = 0; mt < 2; mt++) {
                us hh[4], ll[4];
#pragma unroll
                for (int r = 0; r < 4; r++) {
                    float p = __expf(c[bt][mt][r]) * (bt ? fb[r] : fa[r]);
                    split2(p, &hh[r], &ll[r]);
                }
                uint2 v;
                v.x = (unsigned)hh[0] | ((unsigned)hh[1] << 16);
                v.y = (unsigned)hh[2] | ((unsigned)hh[3] << 16);
                *(uint2*)(Ph + (mt * 16 + lr) * PST + bt * 16 + g * 4) = v;
                v.x = (unsigned)ll[0] | ((unsigned)ll[1] << 16);
                v.y = (unsigned)ll[2] | ((unsigned)ll[3] << 16);
                *(uint2*)(Pl + (mt * 16 + lr) * PST + bt * 16 + g * 4) = v;
            }
        }
        bf8 pah[2], pal[2];
#pragma unroll
        for (int mt = 0; mt < 2; mt++) {
            pah[mt] = *(const bf8*)(Ph + (mt * 16 + lr) * PST + g * 8);
            pal[mt] = *(const bf8*)(Pl + (mt * 16 + lr) * PST + g * 8);
        }
        if (t + 1 < NT) { VMWAIT(4); } else { VMWAIT(0); }
        SBAR();   // V(t) landed
#pragma unroll
        for (int dt = 0; dt < 8; dt++) {
            bf8 vhh = *(const bf8*)(V + (dt * 16 + lr) * 32
                                      + ((g ^ ((lr >> 1) & 3)) * 8));
            acc[0][dt] = MFMA(pah[0], vhh, acc[0][dt], 0, 0, 0);
            acc[0][dt] = MFMA(pal[0], vhh, acc[0][dt], 0, 0, 0);
            acc[1][dt] = MFMA(pah[1], vhh, acc[1][dt], 0, 0, 0);
            acc[1][dt] = MFMA(pal[1], vhh, acc[1][dt], 0, 0, 0);
        }
        if (t + 1 < NT) {
            SBAR();   // PV reads of V done; Q[cur] reads done
            STAGE_VH(t + 1);
        }
        cur ^= 1;
    }
    // epilogue: new = memory + acc; L2-normalize; write memw_hi/lo + memwT_hi
    float n2[2][4];
#pragma unroll
    for (int t = 0; t < 2; t++)
#pragma unroll
        for (int r = 0; r < 4; r++) n2[t][r] = 0.f;
#pragma unroll
    for (int t = 0; t < 2; t++)
#pragma unroll
        for (int dt = 0; dt < 8; dt++)
#pragma unroll
            for (int r = 0; r < 4; r++) {
                float v = acc[t][dt][r]
                        + memory[(mrow + t * 16 + g * 4 + r) * H + dt * 16 + lr];
                acc[t][dt][r] = v;
                n2[t][r] += v * v;
            }
#pragma unroll
    for (int t = 0; t < 2; t++)
#pragma unroll
        for (int r = 0; r < 4; r++) {
#pragma unroll
            for (int x = 1; x < 16; x <<= 1) n2[t][r] += __shfl_xor(n2[t][r], x);
            n2[t][r] = 1.f / fmaxf(sqrtf(n2[t][r]), 1e-12f);
        }
#pragma unroll
    for (int t = 0; t < 2; t++)
#pragma unroll
        for (int dt = 0; dt < 8; dt++)
#pragma unroll
            for (int r = 0; r < 4; r++) {
                float vv = acc[t][dt][r] * n2[t][r];
                us h = f2bf(vv);
                memw_hi[(mrow + t * 16 + g * 4 + r) * H + dt * 16 + lr] = h;
                memw_lo[(mrow + t * 16 + g * 4 + r) * H + dt * 16 + lr]
                    = f2bf(vv - bf2f(h));
            }
    __syncthreads();
#pragma unroll
    for (int t = 0; t < 2; t++)
#pragma unroll
        for (int dt = 0; dt < 8; dt++)
#pragma unroll
            for (int r = 0; r < 4; r++) {
                float vv = acc[t][dt][r] * n2[t][r];
                lds[(dt * 16 + lr) * 136 + w * 32 + t * 16 + g * 4 + r] = f2bf(vv);
            }
    __syncthreads();
    {
        const int d = tid >> 1, seg = tid & 1;
        uint4* dq = (uint4*)(memwT_hi + (size_t)d * M + blockIdx.x * 128 + seg * 64);
        const uint4* sp = (const uint4*)(lds + d * 136 + seg * 64);
#pragma unroll
        for (int j = 0; j < 8; j++) dq[j] = sp[j];
    }
}

// ---------------- K7: flash read: fused stats2 + PV over m-chunks ------------
__global__ __launch_bounds__(256) void k_fread(const us* __restrict__ memw_hi,
        const us* __restrict__ memw_lo, const us* __restrict__ memwT_hi,
        const us* __restrict__ qt_hi, const us* __restrict__ qt_lo,
        float* __restrict__ part, float* __restrict__ pmax2,
        float* __restrict__ psum2, int mchunk) {
    __shared__ us lds[29696];
    const int tid = threadIdx.x;
    const int w = tid >> 6, l = tid & 63;
    const int lr = l & 15, g = l >> 4;
    const int brow = blockIdx.x * 128 + w * 32;
    const int m0b = blockIdx.y * mchunk;
    const int rq = l >> 4, cq = l & 15;
    const int rv = l >> 2, cv = l & 3;
    bf8 qh[2][4], ql[2][4];
#pragma unroll
    for (int bt = 0; bt < 2; bt++)
#pragma unroll
        for (int kk = 0; kk < 4; kk++) {
            const int o = (brow + bt * 16 + lr) * H + kk * 32 + g * 8;
            qh[bt][kk] = ldb(qt_hi + o);
            ql[bt][kk] = ldb(qt_lo + o);
        }
    f32x4 acc[2][8];
#pragma unroll
    for (int bt = 0; bt < 2; bt++)
#pragma unroll
        for (int dt = 0; dt < 8; dt++) acc[bt][dt] = (f32x4){0.f, 0.f, 0.f, 0.f};
    float mb0 = 0.f, sm0 = 0.f, mb1 = 0.f, sm1 = 0.f;
    us* Ph = lds + 20480 + w * 2304;
    us* Pl = Ph + 1152;
    auto STAGE_MW = [&](int t, int bi) {
        const int m0 = m0b + t * 32;
        us* Q = lds + bi * 8192;
#pragma unroll
        for (int i = 0; i < 4; i++) {
            const int id = w * 4 + i;
            const int ii = id & 7;
            const int r = ii * 4 + rq;
            const int cc = cq ^ (r & 7);
            gload16((id < 8 ? memw_hi : memw_lo) + (size_t)(m0 + r) * H + cc * 8,
                    Q + (id < 8 ? 0 : 4096) + ii * 512);
        }
    };
    auto STAGE_WT = [&](int t) {
        const int m0 = m0b + t * 32;
        us* V = lds + 16384;
#pragma unroll
        for (int i = 0; i < 2; i++) {
            const int j = w * 2 + i;
            const int r = j * 16 + rv;
            const int cc = cv ^ ((rv >> 1) & 3);
            gload16(memwT_hi + (size_t)r * M + m0 + cc * 8, V + j * 512);
        }
    };
    STAGE_MW(0, 0);
    STAGE_WT(0);
    int cur = 0;
    const int NT = mchunk / 32;
    const us* V = lds + 16384;
    for (int t = 0; t < NT; t++) {
        if (t + 1 < NT) { STAGE_MW(t + 1, cur ^ 1); VMWAIT(6); }
        else { VMWAIT(2); }
        SBAR();   // memw tile t landed
        const us* Q = lds + cur * 8192;
        f32x4 c[2][2];
#pragma unroll
        for (int mt = 0; mt < 2; mt++)
#pragma unroll
            for (int bt = 0; bt < 2; bt++) c[mt][bt] = (f32x4){0.f, 0.f, 0.f, 0.f};
#pragma unroll
        for (int kk = 0; kk < 4; kk++) {
            const int co = ((kk * 4 + g) ^ (lr & 7)) * 8;
            bf8 a0h = *(const bf8*)(Q + lr * 128 + co);
            bf8 a0l = *(const bf8*)(Q + 4096 + lr * 128 + co);
            bf8 a1h = *(const bf8*)(Q + (16 + lr) * 128 + co);
            bf8 a1l = *(const bf8*)(Q + 4096 + (16 + lr) * 128 + co);
            c[0][0] = MFMA(a0h, qh[0][kk], c[0][0], 0, 0, 0);
            c[0][0] = MFMA(a0l, qh[0][kk], c[0][0], 0, 0, 0);
            c[0][0] = MFMA(a0h, ql[0][kk], c[0][0], 0, 0, 0);
            c[0][1] = MFMA(a0h, qh[1][kk], c[0][1], 0, 0, 0);
            c[0][1] = MFMA(a0l, qh[1][kk], c[0][1], 0, 0, 0);
            c[0][1] = MFMA(a0h, ql[1][kk], c[0][1], 0, 0, 0);
            c[1][0] = MFMA(a1h, qh[0][kk], c[1][0], 0, 0, 0);
            c[1][0] = MFMA(a1l, qh[0][kk], c[1][0], 0, 0, 0);
            c[1][0] = MFMA(a1h, ql[0][kk], c[1][0], 0, 0, 0);
            c[1][1] = MFMA(a1h, qh[1][kk], c[1][1], 0, 0, 0);
            c[1][1] = MFMA(a1l, qh[1][kk], c[1][1], 0, 0, 0);
            c[1][1] = MFMA(a1h, ql[1][kk], c[1][1], 0, 0, 0);
        }
        float s[2][2][4];
        float lmax0 = -INFINITY, lmax1 = -INFINITY;
#pragma unroll
        for (int mt = 0; mt < 2; mt++)
#pragma unroll
            for (int r = 0; r < 4; r++) {
                s[mt][0][r] = c[mt][0][r] * SCALE2;
                s[mt][1][r] = c[mt][1][r] * SCALE2;
                lmax0 = fmaxf(lmax0, s[mt][0][r]);
                lmax1 = fmaxf(lmax1, s[mt][1][r]);
            }
        lmax0 = fmaxf(lmax0, __shfl_xor(lmax0, 16));
        lmax0 = fmaxf(lmax0, __shfl_xor(lmax0, 32));
        lmax1 = fmaxf(lmax1, __shfl_xor(lmax1, 16));
        lmax1 = fmaxf(lmax1, __shfl_xor(lmax1, 32));
        if (__any((lmax0 > mb0 + 8.f) || (lmax1 > mb1 + 8.f))) {
            float nm0 = fmaxf(mb0, lmax0), f0 = __expf(mb0 - nm0);
            float nm1 = fmaxf(mb1, lmax1), f1 = __expf(mb1 - nm1);
            sm0 *= f0; sm1 *= f1;
            float fr0[4], fr1[4];
#pragma unroll
            for (int r = 0; r < 4; r++) {
                fr0[r] = __shfl(f0, g * 4 + r);
                fr1[r] = __shfl(f1, g * 4 + r);
            }
#pragma unroll
            for (int dt = 0; dt < 8; dt++)
#pragma unroll
                for (int r = 0; r < 4; r++) {
                    acc[0][dt][r] *= fr0[r];
                    acc[1][dt][r] *= fr1[r];
                }
            mb0 = nm0; mb1 = nm1;
        }
#pragma unroll
        for (int bt = 0; bt < 2; bt++) {
            const float mbx = bt ? mb1 : mb0;
#pragma unroll
            for (int mt = 0; mt < 2; mt++) {
                us hh[4], ll[4];
#pragma unroll
                for (int r = 0; r < 4; r++) {
                    float p = __expf(s[mt][bt][r] - mbx);
                    if (bt) sm1 += p; else sm0 += p;
                    split2(p, &hh[r], &ll[r]);
                }
                uint2 v;
                v.x = (unsigned)hh[0] | ((unsigned)hh[1] << 16);
                v.y = (unsigned)hh[2] | ((unsigned)hh[3] << 16);
                *(uint2*)(Ph + (bt * 16 + lr) * PST + mt * 16 + g * 4) = v;
                v.x = (unsigned)ll[0] | ((unsigned)ll[1] << 16);
                v.y = (unsigned)ll[2] | ((unsigned)ll[3] << 16);
                *(uint2*)(Pl + (bt * 16 + lr) * PST + mt * 16 + g * 4) = v;
            }
        }
        bf8 pah[2], pal[2];
#pragma unroll
        for (int bt = 0; bt < 2; bt++) {
            pah[bt] = *(const bf8*)(Ph + (bt * 16 + lr) * PST + g * 8);
            pal[bt] = *(const bf8*)(Pl + (bt * 16 + lr) * PST + g * 8);
        }
        if (t + 1 < NT) { VMWAIT(4); } else { VMWAIT(0); }
        SBAR();   // memwT tile t landed
#pragma unroll
        for (int dt = 0; dt < 8; dt++) {
            bf8 th = *(const bf8*)(V + (dt * 16 + lr) * 32
                                     + ((g ^ ((lr >> 1) & 3)) * 8));
            acc[0][dt] = MFMA(pah[0], th, acc[0][dt], 0, 0, 0);
            acc[0][dt] = MFMA(pal[0], th, acc[0][dt], 0, 0, 0);
            acc[1][dt] = MFMA(pah[1], th, acc[1][dt], 0, 0, 0);
            acc[1][dt] = MFMA(pal[1], th, acc[1][dt], 0, 0, 0);
        }
        if (t + 1 < NT) {
            SBAR();   // PV reads done
            STAGE_WT(t + 1);
        }
        cur ^= 1;
    }
    sm0 += __shfl_xor(sm0, 16); sm0 += __shfl_xor(sm0, 32);
    sm1 += __shfl_xor(sm1, 16); sm1 += __shfl_xor(sm1, 32);
    if (g == 0) {
        pmax2[(size_t)blockIdx.y * B + brow + lr] = mb0;
        psum2[(size_t)blockIdx.y * B + brow + lr] = sm0;
        pmax2[(size_t)blockIdx.y * B + brow + 16 + lr] = mb1;
        psum2[(size_t)blockIdx.y * B + brow + 16 + lr] = sm1;
    }
    float* rp = part + (size_t)blockIdx.y * B * H;
#pragma unroll
    for (int bt = 0; bt < 2; bt++)
#pragma unroll
        for (int dt = 0; dt < 8; dt++)
#pragma unroll
            for (int r = 0; r < 4; r++)
                rp[(size_t)(brow + bt * 16 + g * 4 + r) * H + dt * 16 + lr] =
                    acc[bt][dt][r];
}

// ---------------- K8: per-b chunk weights ------------------------------------
__global__ __launch_bounds__(256) void k_fstats(const float* __restrict__ pmax2,
        const float* __restrict__ psum2, float* __restrict__ wc, int nc) {
    const int b = blockIdx.x * 256 + threadIdx.x;
    float gm = -INFINITY;
    for (int c = 0; c < nc; c++) gm = fmaxf(gm, pmax2[(size_t)c * B + b]);
    float z = 0.f;
    for (int c = 0; c < nc; c++)
        z += psum2[(size_t)c * B + b] * __expf(pmax2[(size_t)c * B + b] - gm);
    const float zi = 1.f / z;
    for (int c = 0; c < nc; c++)
        wc[(size_t)c * B + b] = __expf(pmax2[(size_t)c * B + b] - gm) * zi;
}

// ---------------- K9: weighted combine -> out --------------------------------
__global__ __launch_bounds__(256) void k_fcombine(const float* __restrict__ part,
        const float* __restrict__ wc, float* __restrict__ out, int nc) {
    const int i = blockIdx.x * 256 + threadIdx.x;
    const int b = i >> 7;
    float s = 0.f;
    for (int c = 0; c < nc; c++) s += part[(size_t)c * B * H + i] * wc[(size_t)c * B + b];
    out[i] = s;
}

extern "C" void kernel_launch(void* const* d_in, const int* in_sizes, int n_in,
                              void* d_out, int out_size, void* d_ws, size_t ws_size,
                              hipStream_t stream) {
    const float* ts     = (const float*)d_in[0];
    const float* inp    = (const float*)d_in[1];
    const float* memory = (const float*)d_in[2];
    const float* w_t    = (const float*)d_in[3];
    const float* b_t    = (const float*)d_in[4];
    const float* Wq     = (const float*)d_in[5];
    const float* Wk     = (const float*)d_in[6];
    const float* Wv     = (const float*)d_in[7];
    float* out = (float*)d_out;

    char* p = (char*)d_ws;
    auto alloc = [&](size_t bytes) { char* r = p; p += (bytes + 255) & ~(size_t)255; return r; };
    us* mem_hi   = (us*)alloc((size_t)M * H * 2);
    us* mem_lo   = (us*)alloc((size_t)M * H * 2);
    us* memw_hi  = (us*)alloc((size_t)M * H * 2);
    us* memw_lo  = (us*)alloc((size_t)M * H * 2);
    us* memwT_hi = (us*)alloc((size_t)M * H * 2);
    us* qt_hi    = (us*)alloc((size_t)B * H * 2);
    us* qt_lo    = (us*)alloc((size_t)B * H * 2);
    us* vhT_hi   = (us*)alloc((size_t)B * H * 2);
    float* vh    = (float*)alloc((size_t)B * H * 4);
    float* pmax  = (float*)alloc((size_t)B * SC * 4);
    float* psum  = (float*)alloc((size_t)B * SC * 4);
    float* ffac  = (float*)alloc((size_t)B * 4);
    size_t remain = ws_size - (size_t)(p - (char*)d_ws);
    int NC = 1;
    for (int c = 32; c >= 1; c >>= 1) {
        size_t need = (size_t)c * B * H * 4 + 3 * (size_t)c * B * 4 + 4096;
        if (need <= remain) { NC = c; break; }
    }
    float* pmax2 = (float*)alloc((size_t)NC * B * 4);
    float* psum2 = (float*)alloc((size_t)NC * B * 4);
    float* wcb   = (float*)alloc((size_t)NC * B * 4);
    float* part  = (float*)alloc((size_t)NC * B * H * 4);
    const int mchunk = M / NC;

    hipLaunchKernelGGL(k_prep, dim3(B), dim3(128), 0, stream,
                       ts, inp, w_t, b_t, Wq, Wk, Wv, qt_hi, qt_lo, vh);
    hipLaunchKernelGGL(k_splitmem, dim3(2048), dim3(256), 0, stream,
                       memory, mem_hi, mem_lo, M * H);
    hipLaunchKernelGGL(k_tx, dim3(H, B / 256), dim3(256), 0, stream, vh, vhT_hi);
    hipLaunchKernelGGL(k_stats, dim3(B / 128, SC), dim3(256), 0, stream,
                       mem_hi, mem_lo, qt_hi, qt_lo, M / SC, pmax, psum);
    hipLaunchKernelGGL(k_combine1, dim3(B / 256), dim3(256), 0, stream, pmax, psum, ffac);
    hipLaunchKernelGGL(k_update, dim3(M / 128), dim3(256), 0, stream,
                       memory, mem_hi, mem_lo, qt_hi, qt_lo, vhT_hi,
                       ffac, memw_hi, memw_lo, memwT_hi);
    hipLaunchKernelGGL(k_fread, dim3(B / 128, NC), dim3(256), 0, stream,
                       memw_hi, memw_lo, memwT_hi, qt_hi, qt_lo,
                       part, pmax2, psum2, mchunk);
    hipLaunchKernelGGL(k_fstats, dim3(B / 256), dim3(256), 0, stream, pmax2, psum2, wcb, NC);
    hipLaunchKernelGGL(k_fcombine, dim3(B * H / 256), dim3(256), 0, stream, part, wcb, out, NC);
}